// Round 1
// baseline (756.927 us; speedup 1.0000x reference)
//
#include <hip/hip_runtime.h>
#include <hip/hip_bf16.h>

// Problem constants (match reference setup_inputs()).
#define NN   100000   // nodes
#define NE   600000   // edges
#define FIN  128
#define H0   64
#define H1   128
#define DD   512
#define NG   512

// ---------------------------------------------------------------------------
// Histogram: cnt[idx[i]] += 1   (used for in-degree over dst, and batch counts)
__global__ void hist_kernel(const int* __restrict__ idx, int* __restrict__ cnt, int n)
{
    int i = blockIdx.x * blockDim.x + threadIdx.x;
    int stride = gridDim.x * blockDim.x;
    for (; i < n; i += stride) atomicAdd(&cnt[idx[i]], 1);
}

// dinv[i] = 1/sqrt(deg_in[i] + 1)   (+1 = self loop; deg>=1 always)
__global__ void dinv_kernel(const int* __restrict__ deg, float* __restrict__ dinv, int n)
{
    int i = blockIdx.x * blockDim.x + threadIdx.x;
    if (i < n) dinv[i] = 1.0f / sqrtf((float)(deg[i] + 1));
}

// ---------------------------------------------------------------------------
// GEMM1: h0 = x @ Wc0   [100k,128]@[128,64], fused self-loop init:
//        agg0 = h0 * dinv^2
__global__ __launch_bounds__(256) void gemm1_kernel(
    const float* __restrict__ x, const float* __restrict__ W,
    const float* __restrict__ dinv,
    float* __restrict__ h0, float* __restrict__ agg0, int n)
{
    __shared__ float Wl[FIN * H0];                    // 32 KB
    for (int i = threadIdx.x; i < FIN * H0 / 4; i += 256)
        ((float4*)Wl)[i] = ((const float4*)W)[i];
    __syncthreads();

    const int j    = threadIdx.x & 63;                // output col (lane)
    const int rsub = threadIdx.x >> 6;                // 0..3 row within chunk
    for (int rc = blockIdx.x; rc * 4 < n; rc += gridDim.x) {
        const int row = rc * 4 + rsub;                // n % 4 == 0
        const float* xr = x + (size_t)row * FIN;
        float acc = 0.f;
        #pragma unroll
        for (int k = 0; k < FIN; k += 4) {
            float4 xv = *(const float4*)(xr + k);     // wave-broadcast 16B
            acc += xv.x * Wl[(k + 0) * H0 + j];
            acc += xv.y * Wl[(k + 1) * H0 + j];
            acc += xv.z * Wl[(k + 2) * H0 + j];
            acc += xv.w * Wl[(k + 3) * H0 + j];
        }
        const float dv = dinv[row];
        h0  [(size_t)row * H0 + j] = acc;
        agg0[(size_t)row * H0 + j] = acc * dv * dv;
    }
}

// ---------------------------------------------------------------------------
// Edge scatter: acc[dst] += h[src] * dinv[src]*dinv[dst]   (F = 64, lane = feature)
__global__ __launch_bounds__(256) void edge_scatter_kernel(
    const float* __restrict__ h, const float* __restrict__ dinv,
    const int* __restrict__ src, const int* __restrict__ dst,
    float* __restrict__ acc, int ne)
{
    const int lane = threadIdx.x & 63;
    int wid = blockIdx.x * 4 + (threadIdx.x >> 6);
    const int nw = gridDim.x * 4;
    for (int e = wid; e < ne; e += nw) {
        const int s = src[e];
        const int d = dst[e];
        const float c = dinv[s] * dinv[d];
        const float v = h[(size_t)s * H0 + lane];
        atomicAdd(&acc[(size_t)d * H0 + lane], v * c);
    }
}

// ---------------------------------------------------------------------------
// h1 = relu(agg0 + bc0); agg1 = h1 * dinv^2  (self-loop init of layer-2 agg)
__global__ void finalize_init_kernel(
    const float* __restrict__ agg0, const float* __restrict__ bc0,
    const float* __restrict__ dinv,
    float* __restrict__ h1, float* __restrict__ agg1, int n)
{
    int i = blockIdx.x * blockDim.x + threadIdx.x;
    const int total = n * H0;
    const int stride = gridDim.x * blockDim.x;
    for (; i < total; i += stride) {
        const int row = i >> 6;
        const int j   = i & 63;
        const float v = fmaxf(agg0[i] + bc0[j], 0.f);
        h1[i] = v;
        const float dv = dinv[row];
        agg1[i] = v * dv * dv;
    }
}

// ---------------------------------------------------------------------------
// GEMM2 + bias + relu + mean-pool partial sums:
//   h2 = relu(agg1 @ Wc1 + bc1); gsum[batch[row]] += h2[row]
__global__ __launch_bounds__(256) void gemm2_pool_kernel(
    const float* __restrict__ a /*agg1*/, const float* __restrict__ W /*64x128*/,
    const float* __restrict__ bc1, const int* __restrict__ batch,
    float* __restrict__ gsum, int n)
{
    __shared__ float Wl[H0 * H1];                     // 32 KB
    for (int i = threadIdx.x; i < H0 * H1 / 4; i += 256)
        ((float4*)Wl)[i] = ((const float4*)W)[i];
    __syncthreads();

    const int j    = threadIdx.x & 127;               // output col
    const int rsub = threadIdx.x >> 7;                // 0..1
    const float bj = bc1[j];
    for (int rc = blockIdx.x; rc * 2 < n; rc += gridDim.x) {
        const int row = rc * 2 + rsub;                // n % 2 == 0
        const float* ar = a + (size_t)row * H0;
        float acc = bj;
        #pragma unroll
        for (int k = 0; k < H0; k += 4) {
            float4 av = *(const float4*)(ar + k);     // wave-broadcast 16B
            acc += av.x * Wl[(k + 0) * H1 + j];
            acc += av.y * Wl[(k + 1) * H1 + j];
            acc += av.z * Wl[(k + 2) * H1 + j];
            acc += av.w * Wl[(k + 3) * H1 + j];
        }
        acc = fmaxf(acc, 0.f);
        const int b = batch[row];                     // wave-broadcast
        atomicAdd(&gsum[(size_t)b * H1 + j], acc);
    }
}

// ---------------------------------------------------------------------------
// Per-graph MLP head: mean -> Linear(128,512) -> relu-Linear chain -> scalar out
__global__ __launch_bounds__(256) void mlp_kernel(
    const float* __restrict__ gsum, const int* __restrict__ cnt,
    const float* __restrict__ Wf,  const float* __restrict__ bf,
    const float* __restrict__ Wh0, const float* __restrict__ bh0,
    const float* __restrict__ Wh1, const float* __restrict__ bh1,
    const float* __restrict__ Wh2, const float* __restrict__ bh2,
    const float* __restrict__ Wo,  const float* __restrict__ bo,
    float* __restrict__ out)
{
    __shared__ float gm[128];
    __shared__ float e0[512];
    __shared__ float e1[256];
    __shared__ float e2[128];
    __shared__ float e3[64];
    const int gi = blockIdx.x;
    const int t  = threadIdx.x;

    if (t < 128) {
        const int c = cnt[gi];
        gm[t] = gsum[gi * 128 + t] * (1.0f / (float)max(c, 1));
    }
    __syncthreads();

    for (int jj = t; jj < 512; jj += 256) {           // e0 = gm@Wf + bf (no relu)
        float acc = bf[jj];
        for (int k = 0; k < 128; ++k) acc += gm[k] * Wf[k * 512 + jj];
        e0[jj] = acc;
    }
    __syncthreads();

    {                                                 // e1 = relu(e0@Wh0 + bh0)
        float acc = bh0[t & 255];
        for (int k = 0; k < 512; ++k) acc += e0[k] * Wh0[k * 256 + (t & 255)];
        if (t < 256) e1[t] = fmaxf(acc, 0.f);
    }
    __syncthreads();

    if (t < 128) {                                    // e2 = relu(e1@Wh1 + bh1)
        float acc = bh1[t];
        for (int k = 0; k < 256; ++k) acc += e1[k] * Wh1[k * 128 + t];
        e2[t] = fmaxf(acc, 0.f);
    }
    __syncthreads();

    if (t < 64) {                                     // e3 = relu(e2@Wh2 + bh2)
        float acc = bh2[t];
        for (int k = 0; k < 128; ++k) acc += e2[k] * Wh2[k * 64 + t];
        e3[t] = fmaxf(acc, 0.f);
    }
    __syncthreads();

    if (t < 64) {                                     // out = e3@Wo + bo
        float p = e3[t] * Wo[t];
        #pragma unroll
        for (int off = 32; off > 0; off >>= 1) p += __shfl_down(p, off);
        if (t == 0) out[gi] = p + bo[0];
    }
}

// ---------------------------------------------------------------------------
extern "C" void kernel_launch(void* const* d_in, const int* in_sizes, int n_in,
                              void* d_out, int out_size, void* d_ws, size_t ws_size,
                              hipStream_t stream)
{
    const float* x    = (const float*)d_in[0];
    const int*   src  = (const int*)  d_in[1];
    const int*   dst  = (const int*)  d_in[2];
    const int*   batch= (const int*)  d_in[3];
    const float* Wc0  = (const float*)d_in[4];
    const float* bc0  = (const float*)d_in[5];
    const float* Wc1  = (const float*)d_in[6];
    const float* bc1  = (const float*)d_in[7];
    const float* Wf   = (const float*)d_in[8];
    const float* bf   = (const float*)d_in[9];
    const float* Wh0  = (const float*)d_in[10];
    const float* bh0  = (const float*)d_in[11];
    const float* Wh1  = (const float*)d_in[12];
    const float* bh1  = (const float*)d_in[13];
    const float* Wh2  = (const float*)d_in[14];
    const float* bh2  = (const float*)d_in[15];
    const float* Wo   = (const float*)d_in[16];
    const float* bo   = (const float*)d_in[17];
    float* out = (float*)d_out;

    const int n = NN, ne = NE;

    // Workspace carve-out (~103.5 MB). ws is re-poisoned to 0xAA each call;
    // every accumulator below is either memset here or fully written by a kernel.
    char* ws = (char*)d_ws;
    size_t off = 0;
    auto alloc = [&](size_t bytes) {
        void* p = ws + off;
        off = (off + bytes + 255) & ~(size_t)255;
        return p;
    };
    int*   deg  = (int*)  alloc((size_t)n * 4);
    float* dinv = (float*)alloc((size_t)n * 4);
    float* h0   = (float*)alloc((size_t)n * H0 * 4);
    float* agg0 = (float*)alloc((size_t)n * H0 * 4);
    float* h1   = (float*)alloc((size_t)n * H0 * 4);
    float* agg1 = (float*)alloc((size_t)n * H0 * 4);
    float* gsum = (float*)alloc((size_t)NG * H1 * 4);
    int*   cnt  = (int*)  alloc((size_t)NG * 4);

    hipMemsetAsync(deg,  0, (size_t)n * 4, stream);
    hipMemsetAsync(gsum, 0, (size_t)NG * H1 * 4, stream);
    hipMemsetAsync(cnt,  0, (size_t)NG * 4, stream);

    hist_kernel<<<1024, 256, 0, stream>>>(dst, deg, ne);       // in-degree
    hist_kernel<<<512,  256, 0, stream>>>(batch, cnt, n);      // graph sizes
    dinv_kernel<<<(n + 255) / 256, 256, 0, stream>>>(deg, dinv, n);

    // Layer 1: GEMM first (128->64), then propagate at F=64.
    gemm1_kernel<<<2048, 256, 0, stream>>>(x, Wc0, dinv, h0, agg0, n);
    edge_scatter_kernel<<<8192, 256, 0, stream>>>(h0, dinv, src, dst, agg0, ne);

    // h1 = relu(agg0+bc0); init layer-2 aggregation with self-loop term.
    finalize_init_kernel<<<2048, 256, 0, stream>>>(agg0, bc0, dinv, h1, agg1, n);

    // Layer 2: propagate FIRST at F=64 (A'(hW) == (A'h)W), then GEMM 64->128
    // fused with bias+relu+mean-pool partial sums.
    edge_scatter_kernel<<<8192, 256, 0, stream>>>(h1, dinv, src, dst, agg1, ne);
    gemm2_pool_kernel<<<2048, 256, 0, stream>>>(agg1, Wc1, bc1, batch, gsum, n);

    // Per-graph MLP head.
    mlp_kernel<<<NG, 256, 0, stream>>>(gsum, cnt, Wf, bf, Wh0, bh0,
                                       Wh1, bh1, Wh2, bh2, Wo, bo, out);
}

// Round 3
// 613.872 us; speedup vs baseline: 1.2330x; 1.2330x over previous
//
#include <hip/hip_runtime.h>
#include <hip/hip_bf16.h>

// Problem constants (match reference setup_inputs()).
#define NN   100000   // nodes
#define NE   600000   // edges
#define FIN  128
#define H0   64
#define H1   128
#define NG   512

// ---------------------------------------------------------------------------
// Histogram: cnt[idx[i]] += 1  (in-degree over dst; batch counts)
__global__ void hist_kernel(const int* __restrict__ idx, int* __restrict__ cnt, int n)
{
    int i = blockIdx.x * blockDim.x + threadIdx.x;
    int stride = gridDim.x * blockDim.x;
    for (; i < n; i += stride) atomicAdd(&cnt[idx[i]], 1);
}

// dinv[i] = 1/sqrt(deg_in[i] + 1)   (+1 = self loop)
__global__ void dinv_kernel(const int* __restrict__ deg, float* __restrict__ dinv, int n)
{
    int i = blockIdx.x * blockDim.x + threadIdx.x;
    if (i < n) dinv[i] = 1.0f / sqrtf((float)(deg[i] + 1));
}

// ---------------------------------------------------------------------------
// CSR build: exclusive scan of deg -> rowptr, then counting-sort src by dst.
// scan1: per-block exclusive scan + per-block totals
__global__ __launch_bounds__(256) void scan1_kernel(
    const int* __restrict__ deg, int* __restrict__ rp, int* __restrict__ bsum, int n)
{
    __shared__ int tmp[256];
    const int t = threadIdx.x;
    const int i = blockIdx.x * 256 + t;
    int v = (i < n) ? deg[i] : 0;
    tmp[t] = v;
    __syncthreads();
    #pragma unroll
    for (int off = 1; off < 256; off <<= 1) {
        int a = (t >= off) ? tmp[t - off] : 0;
        __syncthreads();
        tmp[t] += a;
        __syncthreads();
    }
    if (i < n) rp[i] = tmp[t] - v;              // exclusive within block
    if (t == 255) bsum[blockIdx.x] = tmp[255];  // block total
}

// scan2: single block exclusive scan of block totals (nb <= 512)
__global__ __launch_bounds__(512) void scan2_kernel(
    const int* __restrict__ bsum, int* __restrict__ boff, int nb)
{
    __shared__ int tmp[512];
    const int t = threadIdx.x;
    int v = (t < nb) ? bsum[t] : 0;
    tmp[t] = v;
    __syncthreads();
    #pragma unroll
    for (int off = 1; off < 512; off <<= 1) {
        int a = (t >= off) ? tmp[t - off] : 0;
        __syncthreads();
        tmp[t] += a;
        __syncthreads();
    }
    if (t < nb) boff[t] = tmp[t] - v;
}

// scan3: add block offsets; also copy to the fill cursor array.
__global__ __launch_bounds__(256) void scan3_kernel(
    int* __restrict__ rp, int* __restrict__ wcur, const int* __restrict__ boff, int n)
{
    const int i = blockIdx.x * 256 + threadIdx.x;
    if (i < n) {
        const int v = rp[i] + boff[blockIdx.x];
        rp[i] = v;
        wcur[i] = v;
    }
}

// fill: csr[rowptr[d] + k] = src (k = arrival order, nondeterministic but sums ok)
__global__ void fill_kernel(const int* __restrict__ src, const int* __restrict__ dst,
                            int* __restrict__ wcur, int* __restrict__ csr, int ne)
{
    int i = blockIdx.x * blockDim.x + threadIdx.x;
    const int stride = gridDim.x * blockDim.x;
    for (; i < ne; i += stride) {
        const int d = dst[i];
        const int p = atomicAdd(&wcur[d], 1);
        csr[p] = src[i];
    }
}

// ---------------------------------------------------------------------------
// GEMM1: h0s[row] = (x[row] @ Wc0) * dinv[row]   [100k,128]@[128,64]
// 4 rows/thread, 4 independent accumulators (ILP), W in LDS.
__global__ __launch_bounds__(256) void gemm1_kernel(
    const float* __restrict__ x, const float* __restrict__ W,
    const float* __restrict__ dinv, float* __restrict__ h0s, int n)
{
    __shared__ float Wl[FIN * H0];                    // 32 KB, layout [k][j]
    for (int i = threadIdx.x; i < FIN * H0 / 4; i += 256)
        ((float4*)Wl)[i] = ((const float4*)W)[i];
    __syncthreads();

    const int j    = threadIdx.x & 63;
    const int rsub = threadIdx.x >> 6;                // wave id in block, 0..3
    for (int rc = blockIdx.x; rc * 16 < n; rc += gridDim.x) {
        const int row0 = rc * 16 + rsub * 4;          // n % 16 == 0
        const float* xr = x + (size_t)row0 * FIN;
        float a0 = 0.f, a1 = 0.f, a2 = 0.f, a3 = 0.f;
        #pragma unroll
        for (int k = 0; k < FIN; k += 4) {
            const float4 x0 = *(const float4*)(xr + 0 * FIN + k);
            const float4 x1 = *(const float4*)(xr + 1 * FIN + k);
            const float4 x2 = *(const float4*)(xr + 2 * FIN + k);
            const float4 x3 = *(const float4*)(xr + 3 * FIN + k);
            const float w0 = Wl[(k + 0) * H0 + j];
            const float w1 = Wl[(k + 1) * H0 + j];
            const float w2 = Wl[(k + 2) * H0 + j];
            const float w3 = Wl[(k + 3) * H0 + j];
            a0 += x0.x * w0; a0 += x0.y * w1; a0 += x0.z * w2; a0 += x0.w * w3;
            a1 += x1.x * w0; a1 += x1.y * w1; a1 += x1.z * w2; a1 += x1.w * w3;
            a2 += x2.x * w0; a2 += x2.y * w1; a2 += x2.z * w2; a2 += x2.w * w3;
            a3 += x3.x * w0; a3 += x3.y * w1; a3 += x3.z * w2; a3 += x3.w * w3;
        }
        h0s[(size_t)(row0 + 0) * H0 + j] = a0 * dinv[row0 + 0];
        h0s[(size_t)(row0 + 1) * H0 + j] = a1 * dinv[row0 + 1];
        h0s[(size_t)(row0 + 2) * H0 + j] = a2 * dinv[row0 + 2];
        h0s[(size_t)(row0 + 3) * H0 + j] = a3 * dinv[row0 + 3];
    }
}

// ---------------------------------------------------------------------------
// CSR gather (one wave per node, lane = feature).
// Input rows are pre-scaled by dinv[s], so aggregation is a plain sum:
//   t = sum_{s in N(d)} hin[s] + hin[d]      (self loop)
// MODE 0 (layer 1): hout = relu(t*dinv[d] + bias) * dinv[d]   (pre-scale for L2)
// MODE 1 (layer 2): hout = t*dinv[d]                          (agg for GEMM2)
template <int MODE>
__global__ __launch_bounds__(256) void gather_kernel(
    const float* __restrict__ hin, const int* __restrict__ rowptr,
    const int* __restrict__ deg, const int* __restrict__ csr,
    const float* __restrict__ dinv, const float* __restrict__ bias,
    float* __restrict__ hout, int n)
{
    const int lane = threadIdx.x & 63;
    int wid = (blockIdx.x * blockDim.x + threadIdx.x) >> 6;
    const int nw = (gridDim.x * blockDim.x) >> 6;
    for (int d = wid; d < n; d += nw) {
        const int r0  = rowptr[d];
        const int cnt = deg[d];
        float acc = hin[(size_t)d * H0 + lane];       // self loop
        int k = 0;
        for (; k + 1 < cnt; k += 2) {                 // 2-way unroll for MLP
            const int s0 = csr[r0 + k];
            const int s1 = csr[r0 + k + 1];
            acc += hin[(size_t)s0 * H0 + lane];
            acc += hin[(size_t)s1 * H0 + lane];
        }
        if (k < cnt) acc += hin[(size_t)csr[r0 + k] * H0 + lane];
        const float dv = dinv[d];
        if (MODE == 0)
            hout[(size_t)d * H0 + lane] = fmaxf(acc * dv + bias[lane], 0.f) * dv;
        else
            hout[(size_t)d * H0 + lane] = acc * dv;
    }
}

// ---------------------------------------------------------------------------
// GEMM2 + bias + relu + mean-pool partials. 4 rows/thread (8 rows/block-chunk).
// batch is SORTED -> merge pool contributions before atomics.
__global__ __launch_bounds__(256) void gemm2_pool_kernel(
    const float* __restrict__ a /*agg1*/, const float* __restrict__ W /*64x128*/,
    const float* __restrict__ bc1, const int* __restrict__ batch,
    float* __restrict__ gsum, int n)
{
    __shared__ float Wl[H0 * H1];                     // 32 KB, layout [k][j]
    __shared__ float red[H1];
    for (int i = threadIdx.x; i < H0 * H1 / 4; i += 256)
        ((float4*)Wl)[i] = ((const float4*)W)[i];
    __syncthreads();

    const int j    = threadIdx.x & 127;
    const int rsub = threadIdx.x >> 7;                // 0..1
    const float bj = bc1[j];
    for (int rc = blockIdx.x; rc * 8 < n; rc += gridDim.x) {
        const int rb   = rc * 8;                      // n % 8 == 0
        const int row0 = rb + rsub * 4;
        const float* ar = a + (size_t)row0 * H0;
        float a0 = 0.f, a1 = 0.f, a2 = 0.f, a3 = 0.f;
        #pragma unroll
        for (int k = 0; k < H0; k += 4) {
            const float4 x0 = *(const float4*)(ar + 0 * H0 + k);
            const float4 x1 = *(const float4*)(ar + 1 * H0 + k);
            const float4 x2 = *(const float4*)(ar + 2 * H0 + k);
            const float4 x3 = *(const float4*)(ar + 3 * H0 + k);
            const float w0 = Wl[(k + 0) * H1 + j];
            const float w1 = Wl[(k + 1) * H1 + j];
            const float w2 = Wl[(k + 2) * H1 + j];
            const float w3 = Wl[(k + 3) * H1 + j];
            a0 += x0.x * w0; a0 += x0.y * w1; a0 += x0.z * w2; a0 += x0.w * w3;
            a1 += x1.x * w0; a1 += x1.y * w1; a1 += x1.z * w2; a1 += x1.w * w3;
            a2 += x2.x * w0; a2 += x2.y * w1; a2 += x2.z * w2; a2 += x2.w * w3;
            a3 += x3.x * w0; a3 += x3.y * w1; a3 += x3.z * w2; a3 += x3.w * w3;
        }
        const float v0 = fmaxf(a0 + bj, 0.f);
        const float v1 = fmaxf(a1 + bj, 0.f);
        const float v2 = fmaxf(a2 + bj, 0.f);
        const float v3 = fmaxf(a3 + bj, 0.f);
        const int g0 = batch[row0];
        const int g3 = batch[row0 + 3];
        const bool buni = (batch[rb] == batch[rb + 7]);  // whole chunk one graph
        const float s = v0 + v1 + v2 + v3;
        __syncthreads();                              // red[] reuse fence
        if (buni && rsub) red[j] = s;
        __syncthreads();
        if (buni) {
            if (!rsub) atomicAdd(&gsum[(size_t)g0 * H1 + j], s + red[j]);
        } else if (g0 == g3) {
            atomicAdd(&gsum[(size_t)g0 * H1 + j], s);
        } else {
            atomicAdd(&gsum[(size_t)g0 * H1 + j], v0);
            atomicAdd(&gsum[(size_t)batch[row0 + 1] * H1 + j], v1);
            atomicAdd(&gsum[(size_t)batch[row0 + 2] * H1 + j], v2);
            atomicAdd(&gsum[(size_t)batch[row0 + 3] * H1 + j], v3);
        }
    }
}

// ---------------------------------------------------------------------------
// Per-graph MLP head: mean -> Linear(128,512) -> relu-Linear chain -> scalar
__global__ __launch_bounds__(256) void mlp_kernel(
    const float* __restrict__ gsum, const int* __restrict__ cnt,
    const float* __restrict__ Wf,  const float* __restrict__ bf,
    const float* __restrict__ Wh0, const float* __restrict__ bh0,
    const float* __restrict__ Wh1, const float* __restrict__ bh1,
    const float* __restrict__ Wh2, const float* __restrict__ bh2,
    const float* __restrict__ Wo,  const float* __restrict__ bo,
    float* __restrict__ out)
{
    __shared__ float gm[128];
    __shared__ float e0[512];
    __shared__ float e1[256];
    __shared__ float e2[128];
    __shared__ float e3[64];
    const int gi = blockIdx.x;
    const int t  = threadIdx.x;

    if (t < 128) {
        const int c = cnt[gi];
        gm[t] = gsum[gi * 128 + t] * (1.0f / (float)max(c, 1));
    }
    __syncthreads();

    for (int jj = t; jj < 512; jj += 256) {           // e0 = gm@Wf + bf (no relu)
        float acc = bf[jj];
        for (int k = 0; k < 128; ++k) acc += gm[k] * Wf[k * 512 + jj];
        e0[jj] = acc;
    }
    __syncthreads();

    {                                                 // e1 = relu(e0@Wh0 + bh0)
        float acc = bh0[t & 255];
        for (int k = 0; k < 512; ++k) acc += e0[k] * Wh0[k * 256 + (t & 255)];
        if (t < 256) e1[t] = fmaxf(acc, 0.f);
    }
    __syncthreads();

    if (t < 128) {                                    // e2 = relu(e1@Wh1 + bh1)
        float acc = bh1[t];
        for (int k = 0; k < 256; ++k) acc += e1[k] * Wh1[k * 128 + t];
        e2[t] = fmaxf(acc, 0.f);
    }
    __syncthreads();

    if (t < 64) {                                     // e3 = relu(e2@Wh2 + bh2)
        float acc = bh2[t];
        for (int k = 0; k < 128; ++k) acc += e2[k] * Wh2[k * 64 + t];
        e3[t] = fmaxf(acc, 0.f);
    }
    __syncthreads();

    if (t < 64) {                                     // out = e3@Wo + bo
        float p = e3[t] * Wo[t];
        #pragma unroll
        for (int off = 32; off > 0; off >>= 1) p += __shfl_down(p, off);
        if (t == 0) out[gi] = p + bo[0];
    }
}

// ---------------------------------------------------------------------------
extern "C" void kernel_launch(void* const* d_in, const int* in_sizes, int n_in,
                              void* d_out, int out_size, void* d_ws, size_t ws_size,
                              hipStream_t stream)
{
    const float* x    = (const float*)d_in[0];
    const int*   src  = (const int*)  d_in[1];
    const int*   dst  = (const int*)  d_in[2];
    const int*   batch= (const int*)  d_in[3];
    const float* Wc0  = (const float*)d_in[4];
    const float* bc0  = (const float*)d_in[5];
    const float* Wc1  = (const float*)d_in[6];
    const float* bc1  = (const float*)d_in[7];
    const float* Wf   = (const float*)d_in[8];
    const float* bf   = (const float*)d_in[9];
    const float* Wh0  = (const float*)d_in[10];
    const float* bh0  = (const float*)d_in[11];
    const float* Wh1  = (const float*)d_in[12];
    const float* bh1  = (const float*)d_in[13];
    const float* Wh2  = (const float*)d_in[14];
    const float* bh2  = (const float*)d_in[15];
    const float* Wo   = (const float*)d_in[16];
    const float* bo   = (const float*)d_in[17];
    float* out = (float*)d_out;

    const int n = NN, ne = NE;
    const int nblk = (n + 255) / 256;   // 391 scan blocks

    // Workspace carve-out (~82 MB); everything is memset or fully overwritten.
    char* ws = (char*)d_ws;
    size_t off = 0;
    auto alloc = [&](size_t bytes) {
        void* p = ws + off;
        off = (off + bytes + 255) & ~(size_t)255;
        return p;
    };
    int*   deg    = (int*)  alloc((size_t)n * 4);
    float* dinv   = (float*)alloc((size_t)n * 4);
    int*   rowptr = (int*)  alloc((size_t)n * 4);
    int*   wcur   = (int*)  alloc((size_t)n * 4);
    int*   bsum   = (int*)  alloc(512 * 4);
    int*   boff   = (int*)  alloc(512 * 4);
    int*   csr    = (int*)  alloc((size_t)ne * 4);
    float* h0s    = (float*)alloc((size_t)n * H0 * 4);
    float* h1s    = (float*)alloc((size_t)n * H0 * 4);
    float* agg1   = (float*)alloc((size_t)n * H0 * 4);
    float* gsum   = (float*)alloc((size_t)NG * H1 * 4);
    int*   cnt    = (int*)  alloc((size_t)NG * 4);

    hipMemsetAsync(deg,  0, (size_t)n * 4, stream);
    hipMemsetAsync(gsum, 0, (size_t)NG * H1 * 4, stream);
    hipMemsetAsync(cnt,  0, (size_t)NG * 4, stream);

    // Degrees + batch counts + dinv.
    hist_kernel<<<1024, 256, 0, stream>>>(dst, deg, ne);
    hist_kernel<<<512,  256, 0, stream>>>(batch, cnt, n);
    dinv_kernel<<<nblk, 256, 0, stream>>>(deg, dinv, n);

    // CSR build (once, reused by both layers).
    scan1_kernel<<<nblk, 256, 0, stream>>>(deg, rowptr, bsum, n);
    scan2_kernel<<<1, 512, 0, stream>>>(bsum, boff, nblk);
    scan3_kernel<<<nblk, 256, 0, stream>>>(rowptr, wcur, boff, n);
    fill_kernel<<<1024, 256, 0, stream>>>(src, dst, wcur, csr, ne);

    // Layer 1: GEMM (128->64, pre-scaled by dinv), then CSR-gather aggregate.
    gemm1_kernel<<<2048, 256, 0, stream>>>(x, Wc0, dinv, h0s, n);
    gather_kernel<0><<<4096, 256, 0, stream>>>(h0s, rowptr, deg, csr, dinv, bc0, h1s, n);

    // Layer 2: aggregate FIRST (A'(hW) == (A'h)W at F=64), then GEMM 64->128
    // fused with bias+relu+mean-pool.
    gather_kernel<1><<<4096, 256, 0, stream>>>(h1s, rowptr, deg, csr, dinv, bc0, agg1, n);
    gemm2_pool_kernel<<<2048, 256, 0, stream>>>(agg1, Wc1, bc1, batch, gsum, n);

    // Per-graph MLP head.
    mlp_kernel<<<NG, 256, 0, stream>>>(gsum, cnt, Wf, bf, Wh0, bh0,
                                       Wh1, bh1, Wh2, bh2, Wo, bo, out);
}

// Round 6
// 473.598 us; speedup vs baseline: 1.5982x; 1.2962x over previous
//
#include <hip/hip_runtime.h>
#include <hip/hip_bf16.h>

// Problem constants (match reference setup_inputs()).
#define NN   100000   // nodes
#define NE   600000   // edges
#define FIN  128
#define H0   64
#define H1   128
#define NG   512
#define BM   64       // GEMM row-tile

// ---------------------------------------------------------------------------
// Histogram: cnt[idx[i]] += 1  (in-degree over dst; batch counts)
__global__ void hist_kernel(const int* __restrict__ idx, int* __restrict__ cnt, int n)
{
    int i = blockIdx.x * blockDim.x + threadIdx.x;
    int stride = gridDim.x * blockDim.x;
    for (; i < n; i += stride) atomicAdd(&cnt[idx[i]], 1);
}

// dinv[i] = 1/sqrt(deg_in[i] + 1)   (+1 = self loop)
__global__ void dinv_kernel(const int* __restrict__ deg, float* __restrict__ dinv, int n)
{
    int i = blockIdx.x * blockDim.x + threadIdx.x;
    if (i < n) dinv[i] = 1.0f / sqrtf((float)(deg[i] + 1));
}

// ---------------------------------------------------------------------------
// CSR build: exclusive scan of deg -> rowptr, then counting-sort src by dst.
__global__ __launch_bounds__(256) void scan1_kernel(
    const int* __restrict__ deg, int* __restrict__ rp, int* __restrict__ bsum, int n)
{
    __shared__ int tmp[256];
    const int t = threadIdx.x;
    const int i = blockIdx.x * 256 + t;
    int v = (i < n) ? deg[i] : 0;
    tmp[t] = v;
    __syncthreads();
    #pragma unroll
    for (int off = 1; off < 256; off <<= 1) {
        int a = (t >= off) ? tmp[t - off] : 0;
        __syncthreads();
        tmp[t] += a;
        __syncthreads();
    }
    if (i < n) rp[i] = tmp[t] - v;
    if (t == 255) bsum[blockIdx.x] = tmp[255];
}

__global__ __launch_bounds__(512) void scan2_kernel(
    const int* __restrict__ bsum, int* __restrict__ boff, int nb)
{
    __shared__ int tmp[512];
    const int t = threadIdx.x;
    int v = (t < nb) ? bsum[t] : 0;
    tmp[t] = v;
    __syncthreads();
    #pragma unroll
    for (int off = 1; off < 512; off <<= 1) {
        int a = (t >= off) ? tmp[t - off] : 0;
        __syncthreads();
        tmp[t] += a;
        __syncthreads();
    }
    if (t < nb) boff[t] = tmp[t] - v;
}

__global__ __launch_bounds__(256) void scan3_kernel(
    int* __restrict__ rp, int* __restrict__ wcur, const int* __restrict__ boff, int n)
{
    const int i = blockIdx.x * 256 + threadIdx.x;
    if (i < n) {
        const int v = rp[i] + boff[blockIdx.x];
        rp[i] = v;
        wcur[i] = v;
    }
}

__global__ void fill_kernel(const int* __restrict__ src, const int* __restrict__ dst,
                            int* __restrict__ wcur, int* __restrict__ csr, int ne)
{
    int i = blockIdx.x * blockDim.x + threadIdx.x;
    const int stride = gridDim.x * blockDim.x;
    for (; i < ne; i += stride) {
        const int d = dst[i];
        const int p = atomicAdd(&wcur[d], 1);
        csr[p] = src[i];
    }
}

// ---------------------------------------------------------------------------
// GEMM1: h0s[row] = (x[row] @ Wc0) * dinv[row]   [100k,128]@[128,64]
// Coalesced LDS staging of the x tile; compute reads are wave-uniform LDS
// broadcasts (free) + lane-indexed W reads (2-way aliasing = free).
__global__ __launch_bounds__(512) void gemm1_kernel(
    const float* __restrict__ x, const float* __restrict__ W,
    const float* __restrict__ dinv, float* __restrict__ h0s, int n)
{
    __shared__ float Wl[FIN * H0];   // 32 KB [k][j]
    __shared__ float xs[BM * FIN];   // 32 KB [r][k]
    const int t = threadIdx.x;
    for (int i = t; i < FIN * H0 / 4; i += 512)
        ((float4*)Wl)[i] = ((const float4*)W)[i];

    const int lane = t & 63;
    const int w    = t >> 6;                       // 0..7, wave -> 8 rows
    const int ntiles = (n + BM - 1) / BM;

    for (int tile = blockIdx.x; tile < ntiles; tile += gridDim.x) {
        const int row0  = tile * BM;
        const int nrows = min(BM, n - row0);
        __syncthreads();                           // xs reuse fence
        {
            const float4* xg = (const float4*)(x + (size_t)row0 * FIN);
            const int nf4 = nrows * FIN / 4;       // 2048 for full tile
            #pragma unroll
            for (int i = 0; i < 4; ++i) {
                const int idx = t + i * 512;
                if (idx < nf4) ((float4*)xs)[idx] = xg[idx];
            }
        }
        __syncthreads();

        float acc[8] = {0.f,0.f,0.f,0.f,0.f,0.f,0.f,0.f};
        const float* xw = xs + (w * 8) * FIN;
        #pragma unroll 2
        for (int k = 0; k < FIN; k += 4) {
            const float w0 = Wl[(k + 0) * H0 + lane];
            const float w1 = Wl[(k + 1) * H0 + lane];
            const float w2 = Wl[(k + 2) * H0 + lane];
            const float w3 = Wl[(k + 3) * H0 + lane];
            #pragma unroll
            for (int r = 0; r < 8; ++r) {
                const float4 xv = *(const float4*)(xw + r * FIN + k); // uniform bcast
                acc[r] += xv.x * w0; acc[r] += xv.y * w1;
                acc[r] += xv.z * w2; acc[r] += xv.w * w3;
            }
        }
        const int rbase = row0 + w * 8;
        #pragma unroll
        for (int r = 0; r < 8; ++r) {
            const int row = rbase + r;
            if (row < n) h0s[(size_t)row * H0 + lane] = acc[r] * dinv[row];
        }
    }
}

// ---------------------------------------------------------------------------
// CSR gather (one wave per node, lane = feature). Rows pre-scaled by dinv[s]:
//   t = sum_{s in N(d)} hin[s] + hin[d]
// MODE 0: hout = relu(t*dinv[d] + bias) * dinv[d]   MODE 1: hout = t*dinv[d]
template <int MODE>
__global__ __launch_bounds__(256) void gather_kernel(
    const float* __restrict__ hin, const int* __restrict__ rowptr,
    const int* __restrict__ deg, const int* __restrict__ csr,
    const float* __restrict__ dinv, const float* __restrict__ bias,
    float* __restrict__ hout, int n)
{
    const int lane = threadIdx.x & 63;
    int wid = (blockIdx.x * blockDim.x + threadIdx.x) >> 6;
    const int nw = (gridDim.x * blockDim.x) >> 6;
    for (int d = wid; d < n; d += nw) {
        const int r0  = rowptr[d];
        const int cnt = deg[d];
        float acc = hin[(size_t)d * H0 + lane];
        int k = 0;
        for (; k + 1 < cnt; k += 2) {
            const int s0 = csr[r0 + k];
            const int s1 = csr[r0 + k + 1];
            acc += hin[(size_t)s0 * H0 + lane];
            acc += hin[(size_t)s1 * H0 + lane];
        }
        if (k < cnt) acc += hin[(size_t)csr[r0 + k] * H0 + lane];
        const float dv = dinv[d];
        if (MODE == 0)
            hout[(size_t)d * H0 + lane] = fmaxf(acc * dv + bias[lane], 0.f) * dv;
        else
            hout[(size_t)d * H0 + lane] = acc * dv;
    }
}

// ---------------------------------------------------------------------------
// GEMM2 [100k,64]@[64,128] + bias + relu + mean-pool, LDS-staged like gemm1.
// Wave w: col-half ch=w&1 (col = ch*64+lane), row-group rg=w>>1 (16 rows).
__global__ __launch_bounds__(512) void gemm2_pool_kernel(
    const float* __restrict__ a /*agg1*/, const float* __restrict__ W /*64x128*/,
    const float* __restrict__ bc1, const int* __restrict__ batch,
    float* __restrict__ gsum, int n)
{
    __shared__ float Wl[H0 * H1];    // 32 KB [k][j]
    __shared__ float xs[BM * H0];    // 16 KB [r][k]
    __shared__ float red[4][H1];     // 2 KB row-group partials
    __shared__ int   bs[BM];
    const int t = threadIdx.x;
    for (int i = t; i < H0 * H1 / 4; i += 512)
        ((float4*)Wl)[i] = ((const float4*)W)[i];

    const int lane = t & 63;
    const int w    = t >> 6;
    const int ch   = w & 1;
    const int rg   = w >> 1;                       // 0..3
    const int col  = ch * 64 + lane;
    const float bj = bc1[col];
    const int ntiles = (n + BM - 1) / BM;

    for (int tile = blockIdx.x; tile < ntiles; tile += gridDim.x) {
        const int row0  = tile * BM;
        const int nrows = min(BM, n - row0);
        __syncthreads();                           // xs/red/bs reuse fence
        {
            const float4* ag = (const float4*)(a + (size_t)row0 * H0);
            const int nf4 = nrows * H0 / 4;        // 1024 for full tile
            #pragma unroll
            for (int i = 0; i < 2; ++i) {
                const int idx = t + i * 512;
                if (idx < nf4) ((float4*)xs)[idx] = ag[idx];
            }
            if (t < nrows) bs[t] = batch[row0 + t];
        }
        __syncthreads();

        float acc[16];
        #pragma unroll
        for (int r = 0; r < 16; ++r) acc[r] = 0.f;
        const float* xw = xs + (rg * 16) * H0;
        #pragma unroll 2
        for (int k = 0; k < H0; k += 4) {
            const float w0 = Wl[(k + 0) * H1 + col];
            const float w1 = Wl[(k + 1) * H1 + col];
            const float w2 = Wl[(k + 2) * H1 + col];
            const float w3 = Wl[(k + 3) * H1 + col];
            #pragma unroll
            for (int r = 0; r < 16; ++r) {
                const float4 xv = *(const float4*)(xw + r * H0 + k); // uniform bcast
                acc[r] += xv.x * w0; acc[r] += xv.y * w1;
                acc[r] += xv.z * w2; acc[r] += xv.w * w3;
            }
        }

        // Pool. uni is block-uniform -> no divergent barrier.
        const bool uni = (nrows == BM) && (bs[0] == bs[BM - 1]);
        if (uni) {
            float s = 0.f;
            #pragma unroll
            for (int r = 0; r < 16; ++r) s += fmaxf(acc[r] + bj, 0.f);
            red[rg][col] = s;
            __syncthreads();
            if (rg == 0)
                atomicAdd(&gsum[(size_t)bs[0] * H1 + col],
                          red[0][col] + red[1][col] + red[2][col] + red[3][col]);
        } else {
            int gcur = -1; float run = 0.f;
            #pragma unroll
            for (int r = 0; r < 16; ++r) {
                const int row = rg * 16 + r;
                if (row < nrows) {
                    const int g = bs[row];                 // sorted batch
                    const float v = fmaxf(acc[r] + bj, 0.f);
                    if (g != gcur) {
                        if (gcur >= 0) atomicAdd(&gsum[(size_t)gcur * H1 + col], run);
                        gcur = g; run = v;
                    } else run += v;
                }
            }
            if (gcur >= 0) atomicAdd(&gsum[(size_t)gcur * H1 + col], run);
        }
    }
}

// ---------------------------------------------------------------------------
// Per-graph MLP head: mean -> Linear(128,512) -> relu-Linear chain -> scalar
__global__ __launch_bounds__(256) void mlp_kernel(
    const float* __restrict__ gsum, const int* __restrict__ cnt,
    const float* __restrict__ Wf,  const float* __restrict__ bf,
    const float* __restrict__ Wh0, const float* __restrict__ bh0,
    const float* __restrict__ Wh1, const float* __restrict__ bh1,
    const float* __restrict__ Wh2, const float* __restrict__ bh2,
    const float* __restrict__ Wo,  const float* __restrict__ bo,
    float* __restrict__ out)
{
    __shared__ float gm[128];
    __shared__ float e0[512];
    __shared__ float e1[256];
    __shared__ float e2[128];
    __shared__ float e3[64];
    const int gi = blockIdx.x;
    const int t  = threadIdx.x;

    if (t < 128) {
        const int c = cnt[gi];
        gm[t] = gsum[gi * 128 + t] * (1.0f / (float)max(c, 1));
    }
    __syncthreads();

    for (int jj = t; jj < 512; jj += 256) {
        float acc = bf[jj];
        for (int k = 0; k < 128; ++k) acc += gm[k] * Wf[k * 512 + jj];
        e0[jj] = acc;
    }
    __syncthreads();

    {
        float acc = bh0[t];
        for (int k = 0; k < 512; ++k) acc += e0[k] * Wh0[k * 256 + t];
        if (t < 256) e1[t] = fmaxf(acc, 0.f);
    }
    __syncthreads();

    if (t < 128) {
        float acc = bh1[t];
        for (int k = 0; k < 256; ++k) acc += e1[k] * Wh1[k * 128 + t];
        e2[t] = fmaxf(acc, 0.f);
    }
    __syncthreads();

    if (t < 64) {
        float acc = bh2[t];
        for (int k = 0; k < 128; ++k) acc += e2[k] * Wh2[k * 64 + t];
        e3[t] = fmaxf(acc, 0.f);
    }
    __syncthreads();

    if (t < 64) {
        float p = e3[t] * Wo[t];
        #pragma unroll
        for (int off = 32; off > 0; off >>= 1) p += __shfl_down(p, off);
        if (t == 0) out[gi] = p + bo[0];
    }
}

// ---------------------------------------------------------------------------
extern "C" void kernel_launch(void* const* d_in, const int* in_sizes, int n_in,
                              void* d_out, int out_size, void* d_ws, size_t ws_size,
                              hipStream_t stream)
{
    const float* x    = (const float*)d_in[0];
    const int*   src  = (const int*)  d_in[1];
    const int*   dst  = (const int*)  d_in[2];
    const int*   batch= (const int*)  d_in[3];
    const float* Wc0  = (const float*)d_in[4];
    const float* bc0  = (const float*)d_in[5];
    const float* Wc1  = (const float*)d_in[6];
    const float* bc1  = (const float*)d_in[7];
    const float* Wf   = (const float*)d_in[8];
    const float* bf   = (const float*)d_in[9];
    const float* Wh0  = (const float*)d_in[10];
    const float* bh0  = (const float*)d_in[11];
    const float* Wh1  = (const float*)d_in[12];
    const float* bh1  = (const float*)d_in[13];
    const float* Wh2  = (const float*)d_in[14];
    const float* bh2  = (const float*)d_in[15];
    const float* Wo   = (const float*)d_in[16];
    const float* bo   = (const float*)d_in[17];
    float* out = (float*)d_out;

    const int n = NN, ne = NE;
    const int nblk = (n + 255) / 256;   // 391 scan blocks

    char* ws = (char*)d_ws;
    size_t off = 0;
    auto alloc = [&](size_t bytes) {
        void* p = ws + off;
        off = (off + bytes + 255) & ~(size_t)255;
        return p;
    };
    int*   deg    = (int*)  alloc((size_t)n * 4);
    float* dinv   = (float*)alloc((size_t)n * 4);
    int*   rowptr = (int*)  alloc((size_t)n * 4);
    int*   wcur   = (int*)  alloc((size_t)n * 4);
    int*   bsum   = (int*)  alloc(512 * 4);
    int*   boff   = (int*)  alloc(512 * 4);
    int*   csr    = (int*)  alloc((size_t)ne * 4);
    float* h0s    = (float*)alloc((size_t)n * H0 * 4);
    float* h1s    = (float*)alloc((size_t)n * H0 * 4);
    float* agg1   = (float*)alloc((size_t)n * H0 * 4);
    float* gsum   = (float*)alloc((size_t)NG * H1 * 4);
    int*   cnt    = (int*)  alloc((size_t)NG * 4);

    hipMemsetAsync(deg,  0, (size_t)n * 4, stream);
    hipMemsetAsync(gsum, 0, (size_t)NG * H1 * 4, stream);
    hipMemsetAsync(cnt,  0, (size_t)NG * 4, stream);

    // Degrees + batch counts + dinv.
    hist_kernel<<<1024, 256, 0, stream>>>(dst, deg, ne);
    hist_kernel<<<512,  256, 0, stream>>>(batch, cnt, n);
    dinv_kernel<<<nblk, 256, 0, stream>>>(deg, dinv, n);

    // CSR build (once, reused by both layers).
    scan1_kernel<<<nblk, 256, 0, stream>>>(deg, rowptr, bsum, n);
    scan2_kernel<<<1, 512, 0, stream>>>(bsum, boff, nblk);
    scan3_kernel<<<nblk, 256, 0, stream>>>(rowptr, wcur, boff, n);
    fill_kernel<<<1024, 256, 0, stream>>>(src, dst, wcur, csr, ne);

    // Layer 1: GEMM (128->64, pre-scaled by dinv), then CSR-gather aggregate.
    gemm1_kernel<<<512, 512, 0, stream>>>(x, Wc0, dinv, h0s, n);
    gather_kernel<0><<<4096, 256, 0, stream>>>(h0s, rowptr, deg, csr, dinv, bc0, h1s, n);

    // Layer 2: aggregate FIRST (A'(hW) == (A'h)W at F=64), then GEMM 64->128
    // fused with bias+relu+mean-pool.
    gather_kernel<1><<<4096, 256, 0, stream>>>(h1s, rowptr, deg, csr, dinv, bc0, agg1, n);
    gemm2_pool_kernel<<<768, 512, 0, stream>>>(agg1, Wc1, bc1, batch, gsum, n);

    // Per-graph MLP head.
    mlp_kernel<<<NG, 256, 0, stream>>>(gsum, cnt, Wf, bf, Wh0, bh0,
                                       Wh1, bh1, Wh2, bh2, Wo, bo, out);
}

// Round 7
// 428.886 us; speedup vs baseline: 1.7649x; 1.1043x over previous
//
#include <hip/hip_runtime.h>
#include <hip/hip_bf16.h>

// Problem constants (match reference setup_inputs()).
#define NN   100000   // nodes
#define NE   600000   // edges
#define FIN  128
#define H0   64
#define H1   128
#define NG   512
#define BM   64       // GEMM row-tile

// ---------------------------------------------------------------------------
// Histogram: cnt[idx[i]] += 1  (in-degree over dst only; random addresses so
// same-address serialization is mild — unlike the sorted batch array).
__global__ void hist_kernel(const int* __restrict__ idx, int* __restrict__ cnt, int n)
{
    int i = blockIdx.x * blockDim.x + threadIdx.x;
    int stride = gridDim.x * blockDim.x;
    for (; i < n; i += stride) atomicAdd(&cnt[idx[i]], 1);
}

// batch is SORTED -> per-graph counts via two binary searches, no atomics.
// (Replaces the 85 us same-address-atomic histogram; writes every cnt[g],
//  so no memset needed. Empty graphs get 0, matching segment_sum.)
__global__ void batch_count_kernel(const int* __restrict__ batch,
                                   int* __restrict__ cnt, int n)
{
    const int g = blockIdx.x * blockDim.x + threadIdx.x;
    if (g >= NG) return;
    int lo = 0, hi = n;
    while (lo < hi) { const int m = (lo + hi) >> 1; if (batch[m] < g) lo = m + 1; else hi = m; }
    const int start = lo;
    lo = 0; hi = n;
    while (lo < hi) { const int m = (lo + hi) >> 1; if (batch[m] < g + 1) lo = m + 1; else hi = m; }
    cnt[g] = lo - start;
}

// dinv[i] = 1/sqrt(deg_in[i] + 1)   (+1 = self loop)
__global__ void dinv_kernel(const int* __restrict__ deg, float* __restrict__ dinv, int n)
{
    int i = blockIdx.x * blockDim.x + threadIdx.x;
    if (i < n) dinv[i] = 1.0f / sqrtf((float)(deg[i] + 1));
}

// ---------------------------------------------------------------------------
// CSR build: exclusive scan of deg -> rowptr, then counting-sort src by dst.
__global__ __launch_bounds__(256) void scan1_kernel(
    const int* __restrict__ deg, int* __restrict__ rp, int* __restrict__ bsum, int n)
{
    __shared__ int tmp[256];
    const int t = threadIdx.x;
    const int i = blockIdx.x * 256 + t;
    int v = (i < n) ? deg[i] : 0;
    tmp[t] = v;
    __syncthreads();
    #pragma unroll
    for (int off = 1; off < 256; off <<= 1) {
        int a = (t >= off) ? tmp[t - off] : 0;
        __syncthreads();
        tmp[t] += a;
        __syncthreads();
    }
    if (i < n) rp[i] = tmp[t] - v;
    if (t == 255) bsum[blockIdx.x] = tmp[255];
}

__global__ __launch_bounds__(512) void scan2_kernel(
    const int* __restrict__ bsum, int* __restrict__ boff, int nb)
{
    __shared__ int tmp[512];
    const int t = threadIdx.x;
    int v = (t < nb) ? bsum[t] : 0;
    tmp[t] = v;
    __syncthreads();
    #pragma unroll
    for (int off = 1; off < 512; off <<= 1) {
        int a = (t >= off) ? tmp[t - off] : 0;
        __syncthreads();
        tmp[t] += a;
        __syncthreads();
    }
    if (t < nb) boff[t] = tmp[t] - v;
}

__global__ __launch_bounds__(256) void scan3_kernel(
    int* __restrict__ rp, int* __restrict__ wcur, const int* __restrict__ boff, int n)
{
    const int i = blockIdx.x * 256 + threadIdx.x;
    if (i < n) {
        const int v = rp[i] + boff[blockIdx.x];
        rp[i] = v;
        wcur[i] = v;
    }
}

__global__ void fill_kernel(const int* __restrict__ src, const int* __restrict__ dst,
                            int* __restrict__ wcur, int* __restrict__ csr, int ne)
{
    int i = blockIdx.x * blockDim.x + threadIdx.x;
    const int stride = gridDim.x * blockDim.x;
    for (; i < ne; i += stride) {
        const int d = dst[i];
        const int p = atomicAdd(&wcur[d], 1);
        csr[p] = src[i];
    }
}

// ---------------------------------------------------------------------------
// GEMM1: h0s[row] = (x[row] @ Wc0) * dinv[row]   [100k,128]@[128,64]
// Coalesced LDS staging of the x tile; compute reads are wave-uniform LDS
// broadcasts (free) + lane-indexed W reads (2-way aliasing = free).
__global__ __launch_bounds__(512) void gemm1_kernel(
    const float* __restrict__ x, const float* __restrict__ W,
    const float* __restrict__ dinv, float* __restrict__ h0s, int n)
{
    __shared__ float Wl[FIN * H0];   // 32 KB [k][j]
    __shared__ float xs[BM * FIN];   // 32 KB [r][k]
    const int t = threadIdx.x;
    for (int i = t; i < FIN * H0 / 4; i += 512)
        ((float4*)Wl)[i] = ((const float4*)W)[i];

    const int lane = t & 63;
    const int w    = t >> 6;                       // 0..7, wave -> 8 rows
    const int ntiles = (n + BM - 1) / BM;

    for (int tile = blockIdx.x; tile < ntiles; tile += gridDim.x) {
        const int row0  = tile * BM;
        const int nrows = min(BM, n - row0);
        __syncthreads();                           // xs reuse fence
        {
            const float4* xg = (const float4*)(x + (size_t)row0 * FIN);
            const int nf4 = nrows * FIN / 4;       // 2048 for full tile
            #pragma unroll
            for (int i = 0; i < 4; ++i) {
                const int idx = t + i * 512;
                if (idx < nf4) ((float4*)xs)[idx] = xg[idx];
            }
        }
        __syncthreads();

        float acc[8] = {0.f,0.f,0.f,0.f,0.f,0.f,0.f,0.f};
        const float* xw = xs + (w * 8) * FIN;
        #pragma unroll 2
        for (int k = 0; k < FIN; k += 4) {
            const float w0 = Wl[(k + 0) * H0 + lane];
            const float w1 = Wl[(k + 1) * H0 + lane];
            const float w2 = Wl[(k + 2) * H0 + lane];
            const float w3 = Wl[(k + 3) * H0 + lane];
            #pragma unroll
            for (int r = 0; r < 8; ++r) {
                const float4 xv = *(const float4*)(xw + r * FIN + k); // uniform bcast
                acc[r] += xv.x * w0; acc[r] += xv.y * w1;
                acc[r] += xv.z * w2; acc[r] += xv.w * w3;
            }
        }
        const int rbase = row0 + w * 8;
        #pragma unroll
        for (int r = 0; r < 8; ++r) {
            const int row = rbase + r;
            if (row < n) h0s[(size_t)row * H0 + lane] = acc[r] * dinv[row];
        }
    }
}

// ---------------------------------------------------------------------------
// CSR gather (one wave per node, lane = feature). Rows pre-scaled by dinv[s]:
//   t = sum_{s in N(d)} hin[s] + hin[d]
// MODE 0: hout = relu(t*dinv[d] + bias) * dinv[d]   MODE 1: hout = t*dinv[d]
template <int MODE>
__global__ __launch_bounds__(256) void gather_kernel(
    const float* __restrict__ hin, const int* __restrict__ rowptr,
    const int* __restrict__ deg, const int* __restrict__ csr,
    const float* __restrict__ dinv, const float* __restrict__ bias,
    float* __restrict__ hout, int n)
{
    const int lane = threadIdx.x & 63;
    int wid = (blockIdx.x * blockDim.x + threadIdx.x) >> 6;
    const int nw = (gridDim.x * blockDim.x) >> 6;
    for (int d = wid; d < n; d += nw) {
        const int r0  = rowptr[d];
        const int cnt = deg[d];
        float acc = hin[(size_t)d * H0 + lane];
        int k = 0;
        for (; k + 1 < cnt; k += 2) {
            const int s0 = csr[r0 + k];
            const int s1 = csr[r0 + k + 1];
            acc += hin[(size_t)s0 * H0 + lane];
            acc += hin[(size_t)s1 * H0 + lane];
        }
        if (k < cnt) acc += hin[(size_t)csr[r0 + k] * H0 + lane];
        const float dv = dinv[d];
        if (MODE == 0)
            hout[(size_t)d * H0 + lane] = fmaxf(acc * dv + bias[lane], 0.f) * dv;
        else
            hout[(size_t)d * H0 + lane] = acc * dv;
    }
}

// ---------------------------------------------------------------------------
// GEMM2 [100k,64]@[64,128] + bias + relu + mean-pool, LDS-staged like gemm1.
// Wave w: col-half ch=w&1 (col = ch*64+lane), row-group rg=w>>1 (16 rows).
__global__ __launch_bounds__(512) void gemm2_pool_kernel(
    const float* __restrict__ a /*agg1*/, const float* __restrict__ W /*64x128*/,
    const float* __restrict__ bc1, const int* __restrict__ batch,
    float* __restrict__ gsum, int n)
{
    __shared__ float Wl[H0 * H1];    // 32 KB [k][j]
    __shared__ float xs[BM * H0];    // 16 KB [r][k]
    __shared__ float red[4][H1];     // 2 KB row-group partials
    __shared__ int   bs[BM];
    const int t = threadIdx.x;
    for (int i = t; i < H0 * H1 / 4; i += 512)
        ((float4*)Wl)[i] = ((const float4*)W)[i];

    const int lane = t & 63;
    const int w    = t >> 6;
    const int ch   = w & 1;
    const int rg   = w >> 1;                       // 0..3
    const int col  = ch * 64 + lane;
    const float bj = bc1[col];
    const int ntiles = (n + BM - 1) / BM;

    for (int tile = blockIdx.x; tile < ntiles; tile += gridDim.x) {
        const int row0  = tile * BM;
        const int nrows = min(BM, n - row0);
        __syncthreads();                           // xs/red/bs reuse fence
        {
            const float4* ag = (const float4*)(a + (size_t)row0 * H0);
            const int nf4 = nrows * H0 / 4;        // 1024 for full tile
            #pragma unroll
            for (int i = 0; i < 2; ++i) {
                const int idx = t + i * 512;
                if (idx < nf4) ((float4*)xs)[idx] = ag[idx];
            }
            if (t < nrows) bs[t] = batch[row0 + t];
        }
        __syncthreads();

        float acc[16];
        #pragma unroll
        for (int r = 0; r < 16; ++r) acc[r] = 0.f;
        const float* xw = xs + (rg * 16) * H0;
        #pragma unroll 2
        for (int k = 0; k < H0; k += 4) {
            const float w0 = Wl[(k + 0) * H1 + col];
            const float w1 = Wl[(k + 1) * H1 + col];
            const float w2 = Wl[(k + 2) * H1 + col];
            const float w3 = Wl[(k + 3) * H1 + col];
            #pragma unroll
            for (int r = 0; r < 16; ++r) {
                const float4 xv = *(const float4*)(xw + r * H0 + k); // uniform bcast
                acc[r] += xv.x * w0; acc[r] += xv.y * w1;
                acc[r] += xv.z * w2; acc[r] += xv.w * w3;
            }
        }

        // Pool. uni is block-uniform -> no divergent barrier.
        const bool uni = (nrows == BM) && (bs[0] == bs[BM - 1]);
        if (uni) {
            float s = 0.f;
            #pragma unroll
            for (int r = 0; r < 16; ++r) s += fmaxf(acc[r] + bj, 0.f);
            red[rg][col] = s;
            __syncthreads();
            if (rg == 0)
                atomicAdd(&gsum[(size_t)bs[0] * H1 + col],
                          red[0][col] + red[1][col] + red[2][col] + red[3][col]);
        } else {
            int gcur = -1; float run = 0.f;
            #pragma unroll
            for (int r = 0; r < 16; ++r) {
                const int row = rg * 16 + r;
                if (row < nrows) {
                    const int g = bs[row];                 // sorted batch
                    const float v = fmaxf(acc[r] + bj, 0.f);
                    if (g != gcur) {
                        if (gcur >= 0) atomicAdd(&gsum[(size_t)gcur * H1 + col], run);
                        gcur = g; run = v;
                    } else run += v;
                }
            }
            if (gcur >= 0) atomicAdd(&gsum[(size_t)gcur * H1 + col], run);
        }
    }
}

// ---------------------------------------------------------------------------
// Per-graph MLP head: mean -> Linear(128,512) -> relu-Linear chain -> scalar
__global__ __launch_bounds__(256) void mlp_kernel(
    const float* __restrict__ gsum, const int* __restrict__ cnt,
    const float* __restrict__ Wf,  const float* __restrict__ bf,
    const float* __restrict__ Wh0, const float* __restrict__ bh0,
    const float* __restrict__ Wh1, const float* __restrict__ bh1,
    const float* __restrict__ Wh2, const float* __restrict__ bh2,
    const float* __restrict__ Wo,  const float* __restrict__ bo,
    float* __restrict__ out)
{
    __shared__ float gm[128];
    __shared__ float e0[512];
    __shared__ float e1[256];
    __shared__ float e2[128];
    __shared__ float e3[64];
    const int gi = blockIdx.x;
    const int t  = threadIdx.x;

    if (t < 128) {
        const int c = cnt[gi];
        gm[t] = gsum[gi * 128 + t] * (1.0f / (float)max(c, 1));
    }
    __syncthreads();

    for (int jj = t; jj < 512; jj += 256) {
        float acc = bf[jj];
        for (int k = 0; k < 128; ++k) acc += gm[k] * Wf[k * 512 + jj];
        e0[jj] = acc;
    }
    __syncthreads();

    {
        float acc = bh0[t];
        for (int k = 0; k < 512; ++k) acc += e0[k] * Wh0[k * 256 + t];
        if (t < 256) e1[t] = fmaxf(acc, 0.f);
    }
    __syncthreads();

    if (t < 128) {
        float acc = bh1[t];
        for (int k = 0; k < 256; ++k) acc += e1[k] * Wh1[k * 128 + t];
        e2[t] = fmaxf(acc, 0.f);
    }
    __syncthreads();

    if (t < 64) {
        float acc = bh2[t];
        for (int k = 0; k < 128; ++k) acc += e2[k] * Wh2[k * 64 + t];
        e3[t] = fmaxf(acc, 0.f);
    }
    __syncthreads();

    if (t < 64) {
        float p = e3[t] * Wo[t];
        #pragma unroll
        for (int off = 32; off > 0; off >>= 1) p += __shfl_down(p, off);
        if (t == 0) out[gi] = p + bo[0];
    }
}

// ---------------------------------------------------------------------------
extern "C" void kernel_launch(void* const* d_in, const int* in_sizes, int n_in,
                              void* d_out, int out_size, void* d_ws, size_t ws_size,
                              hipStream_t stream)
{
    const float* x    = (const float*)d_in[0];
    const int*   src  = (const int*)  d_in[1];
    const int*   dst  = (const int*)  d_in[2];
    const int*   batch= (const int*)  d_in[3];
    const float* Wc0  = (const float*)d_in[4];
    const float* bc0  = (const float*)d_in[5];
    const float* Wc1  = (const float*)d_in[6];
    const float* bc1  = (const float*)d_in[7];
    const float* Wf   = (const float*)d_in[8];
    const float* bf   = (const float*)d_in[9];
    const float* Wh0  = (const float*)d_in[10];
    const float* bh0  = (const float*)d_in[11];
    const float* Wh1  = (const float*)d_in[12];
    const float* bh1  = (const float*)d_in[13];
    const float* Wh2  = (const float*)d_in[14];
    const float* bh2  = (const float*)d_in[15];
    const float* Wo   = (const float*)d_in[16];
    const float* bo   = (const float*)d_in[17];
    float* out = (float*)d_out;

    const int n = NN, ne = NE;
    const int nblk = (n + 255) / 256;   // 391 scan blocks

    char* ws = (char*)d_ws;
    size_t off = 0;
    auto alloc = [&](size_t bytes) {
        void* p = ws + off;
        off = (off + bytes + 255) & ~(size_t)255;
        return p;
    };
    int*   deg    = (int*)  alloc((size_t)n * 4);
    float* dinv   = (float*)alloc((size_t)n * 4);
    int*   rowptr = (int*)  alloc((size_t)n * 4);
    int*   wcur   = (int*)  alloc((size_t)n * 4);
    int*   bsum   = (int*)  alloc(512 * 4);
    int*   boff   = (int*)  alloc(512 * 4);
    int*   csr    = (int*)  alloc((size_t)ne * 4);
    float* h0s    = (float*)alloc((size_t)n * H0 * 4);
    float* h1s    = (float*)alloc((size_t)n * H0 * 4);
    float* agg1   = (float*)alloc((size_t)n * H0 * 4);
    float* gsum   = (float*)alloc((size_t)NG * H1 * 4);
    int*   cnt    = (int*)  alloc((size_t)NG * 4);

    hipMemsetAsync(deg,  0, (size_t)n * 4, stream);
    hipMemsetAsync(gsum, 0, (size_t)NG * H1 * 4, stream);

    // Degrees (random-address atomics) + batch counts (binary search, no
    // atomics — batch is sorted; the atomic version serialized at 85 us).
    hist_kernel<<<1024, 256, 0, stream>>>(dst, deg, ne);
    batch_count_kernel<<<2, 256, 0, stream>>>(batch, cnt, n);
    dinv_kernel<<<nblk, 256, 0, stream>>>(deg, dinv, n);

    // CSR build (once, reused by both layers).
    scan1_kernel<<<nblk, 256, 0, stream>>>(deg, rowptr, bsum, n);
    scan2_kernel<<<1, 512, 0, stream>>>(bsum, boff, nblk);
    scan3_kernel<<<nblk, 256, 0, stream>>>(rowptr, wcur, boff, n);
    fill_kernel<<<1024, 256, 0, stream>>>(src, dst, wcur, csr, ne);

    // Layer 1: GEMM (128->64, pre-scaled by dinv), then CSR-gather aggregate.
    gemm1_kernel<<<512, 512, 0, stream>>>(x, Wc0, dinv, h0s, n);
    gather_kernel<0><<<4096, 256, 0, stream>>>(h0s, rowptr, deg, csr, dinv, bc0, h1s, n);

    // Layer 2: aggregate FIRST (A'(hW) == (A'h)W at F=64), then GEMM 64->128
    // fused with bias+relu+mean-pool.
    gather_kernel<1><<<4096, 256, 0, stream>>>(h1s, rowptr, deg, csr, dinv, bc0, agg1, n);
    gemm2_pool_kernel<<<768, 512, 0, stream>>>(agg1, Wc1, bc1, batch, gsum, n);

    // Per-graph MLP head.
    mlp_kernel<<<NG, 256, 0, stream>>>(gsum, cnt, Wf, bf, Wh0, bh0,
                                       Wh1, bh1, Wh2, bh2, Wo, bo, out);
}

// Round 9
// 415.877 us; speedup vs baseline: 1.8201x; 1.0313x over previous
//
#include <hip/hip_runtime.h>
#include <hip/hip_bf16.h>

// Problem constants (match reference setup_inputs()).
#define NN   100000   // nodes
#define NE   600000   // edges
#define FIN  128
#define H0   64
#define H1   128
#define NG   512
#define BM   64       // GEMM row-tile

// ---------------------------------------------------------------------------
// Histogram: cnt[idx[i]] += 1  (in-degree over dst only; random addresses so
// same-address serialization is mild — unlike the sorted batch array).
__global__ void hist_kernel(const int* __restrict__ idx, int* __restrict__ cnt, int n)
{
    int i = blockIdx.x * blockDim.x + threadIdx.x;
    int stride = gridDim.x * blockDim.x;
    for (; i < n; i += stride) atomicAdd(&cnt[idx[i]], 1);
}

// batch is SORTED -> per-graph counts via two binary searches, no atomics.
__global__ void batch_count_kernel(const int* __restrict__ batch,
                                   int* __restrict__ cnt, int n)
{
    const int g = blockIdx.x * blockDim.x + threadIdx.x;
    if (g >= NG) return;
    int lo = 0, hi = n;
    while (lo < hi) { const int m = (lo + hi) >> 1; if (batch[m] < g) lo = m + 1; else hi = m; }
    const int start = lo;
    lo = 0; hi = n;
    while (lo < hi) { const int m = (lo + hi) >> 1; if (batch[m] < g + 1) lo = m + 1; else hi = m; }
    cnt[g] = lo - start;
}

// dinv[i] = 1/sqrt(deg_in[i] + 1)   (+1 = self loop)
__global__ void dinv_kernel(const int* __restrict__ deg, float* __restrict__ dinv, int n)
{
    int i = blockIdx.x * blockDim.x + threadIdx.x;
    if (i < n) dinv[i] = 1.0f / sqrtf((float)(deg[i] + 1));
}

// ---------------------------------------------------------------------------
// CSR build: exclusive scan of deg -> rowptr, then counting-sort src by dst.
__global__ __launch_bounds__(256) void scan1_kernel(
    const int* __restrict__ deg, int* __restrict__ rp, int* __restrict__ bsum, int n)
{
    __shared__ int tmp[256];
    const int t = threadIdx.x;
    const int i = blockIdx.x * 256 + t;
    int v = (i < n) ? deg[i] : 0;
    tmp[t] = v;
    __syncthreads();
    #pragma unroll
    for (int off = 1; off < 256; off <<= 1) {
        int a = (t >= off) ? tmp[t - off] : 0;
        __syncthreads();
        tmp[t] += a;
        __syncthreads();
    }
    if (i < n) rp[i] = tmp[t] - v;
    if (t == 255) bsum[blockIdx.x] = tmp[255];
}

__global__ __launch_bounds__(512) void scan2_kernel(
    const int* __restrict__ bsum, int* __restrict__ boff, int nb)
{
    __shared__ int tmp[512];
    const int t = threadIdx.x;
    int v = (t < nb) ? bsum[t] : 0;
    tmp[t] = v;
    __syncthreads();
    #pragma unroll
    for (int off = 1; off < 512; off <<= 1) {
        int a = (t >= off) ? tmp[t - off] : 0;
        __syncthreads();
        tmp[t] += a;
        __syncthreads();
    }
    if (t < nb) boff[t] = tmp[t] - v;
}

__global__ __launch_bounds__(256) void scan3_kernel(
    int* __restrict__ rp, int* __restrict__ wcur, const int* __restrict__ boff, int n)
{
    const int i = blockIdx.x * 256 + threadIdx.x;
    if (i < n) {
        const int v = rp[i] + boff[blockIdx.x];
        rp[i] = v;
        wcur[i] = v;
    }
}

__global__ void fill_kernel(const int* __restrict__ src, const int* __restrict__ dst,
                            int* __restrict__ wcur, int* __restrict__ csr, int ne)
{
    int i = blockIdx.x * blockDim.x + threadIdx.x;
    const int stride = gridDim.x * blockDim.x;
    for (; i < ne; i += stride) {
        const int d = dst[i];
        const int p = atomicAdd(&wcur[d], 1);
        csr[p] = src[i];
    }
}

// ---------------------------------------------------------------------------
// GEMM1: h0s[row] = (x[row] @ Wc0) * dinv[row]   [100k,128]@[128,64]
// Register-tiled 4x4: each ds_read_b128 feeds 16 FMAs (was 4 -> LDS-bound).
// Wave = 16 rows x 64 cols: lane = (rsub 0..3)x(cgrp 0..15); 4 waves, BM=64.
__global__ __launch_bounds__(256) void gemm1_kernel(
    const float* __restrict__ x, const float* __restrict__ W,
    const float* __restrict__ dinv, float* __restrict__ h0s, int n)
{
    __shared__ float Wl[FIN * H0];   // 32 KB [k][j]
    __shared__ float xs[BM * FIN];   // 32 KB [r][k]
    const int t = threadIdx.x;
    for (int i = t; i < FIN * H0 / 4; i += 256)
        ((float4*)Wl)[i] = ((const float4*)W)[i];

    const int lane = t & 63;
    const int w    = t >> 6;              // 0..3
    const int rsub = lane >> 4;           // 0..3
    const int j0   = (lane & 15) * 4;     // col base
    const int wrow = w * 16 + rsub * 4;   // row base within tile
    const int ntiles = (n + BM - 1) / BM;

    for (int tile = blockIdx.x; tile < ntiles; tile += gridDim.x) {
        const int row0  = tile * BM;
        const int nrows = min(BM, n - row0);
        __syncthreads();                  // xs reuse fence
        {
            const float4* xg = (const float4*)(x + (size_t)row0 * FIN);
            const int nf4 = nrows * FIN / 4;          // 2048 full tile
            for (int idx = t; idx < nf4; idx += 256)
                ((float4*)xs)[idx] = xg[idx];
        }
        __syncthreads();

        float acc[4][4] = {};
        const float* xr = xs + wrow * FIN;
        #pragma unroll 4
        for (int k = 0; k < FIN; k += 4) {
            const float4 w0 = *(const float4*)&Wl[(k + 0) * H0 + j0];
            const float4 w1 = *(const float4*)&Wl[(k + 1) * H0 + j0];
            const float4 w2 = *(const float4*)&Wl[(k + 2) * H0 + j0];
            const float4 w3 = *(const float4*)&Wl[(k + 3) * H0 + j0];
            #pragma unroll
            for (int r = 0; r < 4; ++r) {
                const float4 xv = *(const float4*)&xr[r * FIN + k]; // 16-lane bcast
                acc[r][0] += xv.x * w0.x; acc[r][0] += xv.y * w1.x;
                acc[r][0] += xv.z * w2.x; acc[r][0] += xv.w * w3.x;
                acc[r][1] += xv.x * w0.y; acc[r][1] += xv.y * w1.y;
                acc[r][1] += xv.z * w2.y; acc[r][1] += xv.w * w3.y;
                acc[r][2] += xv.x * w0.z; acc[r][2] += xv.y * w1.z;
                acc[r][2] += xv.z * w2.z; acc[r][2] += xv.w * w3.z;
                acc[r][3] += xv.x * w0.w; acc[r][3] += xv.y * w1.w;
                acc[r][3] += xv.z * w2.w; acc[r][3] += xv.w * w3.w;
            }
        }
        #pragma unroll
        for (int r = 0; r < 4; ++r) {
            const int row = row0 + wrow + r;
            if (row < n) {
                const float dv = dinv[row];
                float4 o;
                o.x = acc[r][0] * dv; o.y = acc[r][1] * dv;
                o.z = acc[r][2] * dv; o.w = acc[r][3] * dv;
                *(float4*)&h0s[(size_t)row * H0 + j0] = o;   // 256B/row-group
            }
        }
    }
}

// ---------------------------------------------------------------------------
// CSR gather (one wave per node, lane = feature). Rows pre-scaled by dinv[s]:
//   t = sum_{s in N(d)} hin[s] + hin[d]
// MODE 0: hout = relu(t*dinv[d] + bias) * dinv[d]   MODE 1: hout = t*dinv[d]
template <int MODE>
__global__ __launch_bounds__(256) void gather_kernel(
    const float* __restrict__ hin, const int* __restrict__ rowptr,
    const int* __restrict__ deg, const int* __restrict__ csr,
    const float* __restrict__ dinv, const float* __restrict__ bias,
    float* __restrict__ hout, int n)
{
    const int lane = threadIdx.x & 63;
    int wid = (blockIdx.x * blockDim.x + threadIdx.x) >> 6;
    const int nw = (gridDim.x * blockDim.x) >> 6;
    for (int d = wid; d < n; d += nw) {
        const int r0  = rowptr[d];
        const int cnt = deg[d];
        float acc = hin[(size_t)d * H0 + lane];
        int k = 0;
        for (; k + 1 < cnt; k += 2) {
            const int s0 = csr[r0 + k];
            const int s1 = csr[r0 + k + 1];
            acc += hin[(size_t)s0 * H0 + lane];
            acc += hin[(size_t)s1 * H0 + lane];
        }
        if (k < cnt) acc += hin[(size_t)csr[r0 + k] * H0 + lane];
        const float dv = dinv[d];
        if (MODE == 0)
            hout[(size_t)d * H0 + lane] = fmaxf(acc * dv + bias[lane], 0.f) * dv;
        else
            hout[(size_t)d * H0 + lane] = acc * dv;
    }
}

// ---------------------------------------------------------------------------
// GEMM2 [100k,64]@[64,128] + bias + relu + mean-pool. Register-tiled 4x8.
// Wave = 16 rows x 128 cols (rsub 0..3, cgrp 0..15 x 8 cols); 4 waves, BM=64.
__global__ __launch_bounds__(256) void gemm2_pool_kernel(
    const float* __restrict__ a /*agg1*/, const float* __restrict__ W /*64x128*/,
    const float* __restrict__ bc1, const int* __restrict__ batch,
    float* __restrict__ gsum, int n)
{
    __shared__ float Wl[H0 * H1];    // 32 KB [k][j]
    __shared__ float as[BM * H0];    // 16 KB [r][k]
    __shared__ float red[4][H1];     // 2 KB per-wave col partials
    __shared__ int   bs[BM];
    const int t = threadIdx.x;
    for (int i = t; i < H0 * H1 / 4; i += 256)
        ((float4*)Wl)[i] = ((const float4*)W)[i];

    const int lane = t & 63;
    const int w    = t >> 6;              // 0..3
    const int rsub = lane >> 4;           // 0..3
    const int j0   = (lane & 15) * 8;     // col base (8 cols/thread)
    const int wrow = w * 16 + rsub * 4;   // row base within tile
    const float4 bA = *(const float4*)&bc1[j0];
    const float4 bB = *(const float4*)&bc1[j0 + 4];
    const int ntiles = (n + BM - 1) / BM;

    for (int tile = blockIdx.x; tile < ntiles; tile += gridDim.x) {
        const int row0  = tile * BM;
        const int nrows = min(BM, n - row0);
        __syncthreads();                  // as/red/bs reuse fence
        {
            const float4* ag = (const float4*)(a + (size_t)row0 * H0);
            const int nf4 = nrows * H0 / 4;           // 1024 full tile
            for (int idx = t; idx < nf4; idx += 256)
                ((float4*)as)[idx] = ag[idx];
            if (t < nrows) bs[t] = batch[row0 + t];
        }
        __syncthreads();

        float acc[4][8] = {};
        const float* ar = as + wrow * H0;
        #pragma unroll 4
        for (int k = 0; k < H0; k += 4) {
            float4 wa[4], wb[4];
            #pragma unroll
            for (int kk = 0; kk < 4; ++kk) {
                wa[kk] = *(const float4*)&Wl[(k + kk) * H1 + j0];
                wb[kk] = *(const float4*)&Wl[(k + kk) * H1 + j0 + 4];
            }
            #pragma unroll
            for (int r = 0; r < 4; ++r) {
                const float4 xv = *(const float4*)&ar[r * H0 + k]; // 16-lane bcast
                acc[r][0] += xv.x * wa[0].x; acc[r][0] += xv.y * wa[1].x;
                acc[r][0] += xv.z * wa[2].x; acc[r][0] += xv.w * wa[3].x;
                acc[r][1] += xv.x * wa[0].y; acc[r][1] += xv.y * wa[1].y;
                acc[r][1] += xv.z * wa[2].y; acc[r][1] += xv.w * wa[3].y;
                acc[r][2] += xv.x * wa[0].z; acc[r][2] += xv.y * wa[1].z;
                acc[r][2] += xv.z * wa[2].z; acc[r][2] += xv.w * wa[3].z;
                acc[r][3] += xv.x * wa[0].w; acc[r][3] += xv.y * wa[1].w;
                acc[r][3] += xv.z * wa[2].w; acc[r][3] += xv.w * wa[3].w;
                acc[r][4] += xv.x * wb[0].x; acc[r][4] += xv.y * wb[1].x;
                acc[r][4] += xv.z * wb[2].x; acc[r][4] += xv.w * wb[3].x;
                acc[r][5] += xv.x * wb[0].y; acc[r][5] += xv.y * wb[1].y;
                acc[r][5] += xv.z * wb[2].y; acc[r][5] += xv.w * wb[3].y;
                acc[r][6] += xv.x * wb[0].z; acc[r][6] += xv.y * wb[1].z;
                acc[r][6] += xv.z * wb[2].z; acc[r][6] += xv.w * wb[3].z;
                acc[r][7] += xv.x * wb[0].w; acc[r][7] += xv.y * wb[1].w;
                acc[r][7] += xv.z * wb[2].w; acc[r][7] += xv.w * wb[3].w;
            }
        }

        // bias+relu into per-row values, then pool (batch sorted).
        const float bv[8] = {bA.x, bA.y, bA.z, bA.w, bB.x, bB.y, bB.z, bB.w};
        const bool uni = (nrows == BM) && (bs[0] == bs[BM - 1]); // block-uniform
        if (uni) {
            float s[8];
            #pragma unroll
            for (int c = 0; c < 8; ++c) {
                s[c] = fmaxf(acc[0][c] + bv[c], 0.f) + fmaxf(acc[1][c] + bv[c], 0.f)
                     + fmaxf(acc[2][c] + bv[c], 0.f) + fmaxf(acc[3][c] + bv[c], 0.f);
                s[c] += __shfl_xor(s[c], 16);      // merge rsub pairs
                s[c] += __shfl_xor(s[c], 32);      // all 4 rsubs -> 16-row sum
            }
            if (rsub == 0) {
                #pragma unroll
                for (int c = 0; c < 8; ++c) red[w][j0 + c] = s[c];
            }
            __syncthreads();
            if (t < H1)
                atomicAdd(&gsum[(size_t)bs[0] * H1 + t],
                          red[0][t] + red[1][t] + red[2][t] + red[3][t]);
        } else {
            int gcur = -1; float run[8];
            #pragma unroll
            for (int r = 0; r < 4; ++r) {
                const int row = wrow + r;
                if (row < nrows) {
                    const int g = bs[row];
                    if (g != gcur) {
                        if (gcur >= 0) {
                            #pragma unroll
                            for (int c = 0; c < 8; ++c)
                                atomicAdd(&gsum[(size_t)gcur * H1 + j0 + c], run[c]);
                        }
                        gcur = g;
                        #pragma unroll
                        for (int c = 0; c < 8; ++c) run[c] = fmaxf(acc[r][c] + bv[c], 0.f);
                    } else {
                        #pragma unroll
                        for (int c = 0; c < 8; ++c) run[c] += fmaxf(acc[r][c] + bv[c], 0.f);
                    }
                }
            }
            if (gcur >= 0) {
                #pragma unroll
                for (int c = 0; c < 8; ++c)
                    atomicAdd(&gsum[(size_t)gcur * H1 + j0 + c], run[c]);
            }
        }
    }
}

// ---------------------------------------------------------------------------
// Per-graph MLP head: mean -> Linear(128,512) -> relu-Linear chain -> scalar
__global__ __launch_bounds__(256) void mlp_kernel(
    const float* __restrict__ gsum, const int* __restrict__ cnt,
    const float* __restrict__ Wf,  const float* __restrict__ bf,
    const float* __restrict__ Wh0, const float* __restrict__ bh0,
    const float* __restrict__ Wh1, const float* __restrict__ bh1,
    const float* __restrict__ Wh2, const float* __restrict__ bh2,
    const float* __restrict__ Wo,  const float* __restrict__ bo,
    float* __restrict__ out)
{
    __shared__ float gm[128];
    __shared__ float e0[512];
    __shared__ float e1[256];
    __shared__ float e2[128];
    __shared__ float e3[64];
    const int gi = blockIdx.x;
    const int t  = threadIdx.x;

    if (t < 128) {
        const int c = cnt[gi];
        gm[t] = gsum[gi * 128 + t] * (1.0f / (float)max(c, 1));
    }
    __syncthreads();

    for (int jj = t; jj < 512; jj += 256) {
        float acc = bf[jj];
        for (int k = 0; k < 128; ++k) acc += gm[k] * Wf[k * 512 + jj];
        e0[jj] = acc;
    }
    __syncthreads();

    {
        float acc = bh0[t];
        for (int k = 0; k < 512; ++k) acc += e0[k] * Wh0[k * 256 + t];
        if (t < 256) e1[t] = fmaxf(acc, 0.f);
    }
    __syncthreads();

    if (t < 128) {
        float acc = bh1[t];
        for (int k = 0; k < 256; ++k) acc += e1[k] * Wh1[k * 128 + t];
        e2[t] = fmaxf(acc, 0.f);
    }
    __syncthreads();

    if (t < 64) {
        float acc = bh2[t];
        for (int k = 0; k < 128; ++k) acc += e2[k] * Wh2[k * 64 + t];
        e3[t] = fmaxf(acc, 0.f);
    }
    __syncthreads();

    if (t < 64) {
        float p = e3[t] * Wo[t];
        #pragma unroll
        for (int off = 32; off > 0; off >>= 1) p += __shfl_down(p, off);
        if (t == 0) out[gi] = p + bo[0];
    }
}

// ---------------------------------------------------------------------------
extern "C" void kernel_launch(void* const* d_in, const int* in_sizes, int n_in,
                              void* d_out, int out_size, void* d_ws, size_t ws_size,
                              hipStream_t stream)
{
    const float* x    = (const float*)d_in[0];
    const int*   src  = (const int*)  d_in[1];
    const int*   dst  = (const int*)  d_in[2];
    const int*   batch= (const int*)  d_in[3];
    const float* Wc0  = (const float*)d_in[4];
    const float* bc0  = (const float*)d_in[5];
    const float* Wc1  = (const float*)d_in[6];
    const float* bc1  = (const float*)d_in[7];
    const float* Wf   = (const float*)d_in[8];
    const float* bf   = (const float*)d_in[9];
    const float* Wh0  = (const float*)d_in[10];
    const float* bh0  = (const float*)d_in[11];
    const float* Wh1  = (const float*)d_in[12];
    const float* bh1  = (const float*)d_in[13];
    const float* Wh2  = (const float*)d_in[14];
    const float* bh2  = (const float*)d_in[15];
    const float* Wo   = (const float*)d_in[16];
    const float* bo   = (const float*)d_in[17];
    float* out = (float*)d_out;

    const int n = NN, ne = NE;
    const int nblk = (n + 255) / 256;   // 391 scan blocks

    char* ws = (char*)d_ws;
    size_t off = 0;
    auto alloc = [&](size_t bytes) {
        void* p = ws + off;
        off = (off + bytes + 255) & ~(size_t)255;
        return p;
    };
    int*   deg    = (int*)  alloc((size_t)n * 4);
    float* dinv   = (float*)alloc((size_t)n * 4);
    int*   rowptr = (int*)  alloc((size_t)n * 4);
    int*   wcur   = (int*)  alloc((size_t)n * 4);
    int*   bsum   = (int*)  alloc(512 * 4);
    int*   boff   = (int*)  alloc(512 * 4);
    int*   csr    = (int*)  alloc((size_t)ne * 4);
    float* h0s    = (float*)alloc((size_t)n * H0 * 4);
    float* h1s    = (float*)alloc((size_t)n * H0 * 4);
    float* agg1   = (float*)alloc((size_t)n * H0 * 4);
    float* gsum   = (float*)alloc((size_t)NG * H1 * 4);
    int*   cnt    = (int*)  alloc((size_t)NG * 4);

    hipMemsetAsync(deg,  0, (size_t)n * 4, stream);
    hipMemsetAsync(gsum, 0, (size_t)NG * H1 * 4, stream);

    // Degrees (random-address atomics) + batch counts (binary search).
    hist_kernel<<<1024, 256, 0, stream>>>(dst, deg, ne);
    batch_count_kernel<<<2, 256, 0, stream>>>(batch, cnt, n);
    dinv_kernel<<<nblk, 256, 0, stream>>>(deg, dinv, n);

    // CSR build (once, reused by both layers).
    scan1_kernel<<<nblk, 256, 0, stream>>>(deg, rowptr, bsum, n);
    scan2_kernel<<<1, 512, 0, stream>>>(bsum, boff, nblk);
    scan3_kernel<<<nblk, 256, 0, stream>>>(rowptr, wcur, boff, n);
    fill_kernel<<<1024, 256, 0, stream>>>(src, dst, wcur, csr, ne);

    // Layer 1: GEMM (128->64, pre-scaled by dinv), then CSR-gather aggregate.
    gemm1_kernel<<<1024, 256, 0, stream>>>(x, Wc0, dinv, h0s, n);
    gather_kernel<0><<<4096, 256, 0, stream>>>(h0s, rowptr, deg, csr, dinv, bc0, h1s, n);

    // Layer 2: aggregate FIRST (A'(hW) == (A'h)W at F=64), then GEMM 64->128
    // fused with bias+relu+mean-pool.
    gather_kernel<1><<<4096, 256, 0, stream>>>(h1s, rowptr, deg, csr, dinv, bc0, agg1, n);
    gemm2_pool_kernel<<<1024, 256, 0, stream>>>(agg1, Wc1, bc1, batch, gsum, n);

    // Per-graph MLP head.
    mlp_kernel<<<NG, 256, 0, stream>>>(gsum, cnt, Wf, bf, Wh0, bh0,
                                       Wh1, bh1, Wh2, bh2, Wo, bo, out);
}

// Round 10
// 389.145 us; speedup vs baseline: 1.9451x; 1.0687x over previous
//
#include <hip/hip_runtime.h>
#include <hip/hip_bf16.h>

// Problem constants (match reference setup_inputs()).
#define NN   100000   // nodes
#define NE   600000   // edges
#define FIN  128
#define H0   64
#define H1   128
#define NG   512
#define BM   64       // GEMM row-tile
#define XP   132      // padded xs row stride (FIN+4): breaks 4-row bank alias
#define AP   68       // padded as row stride (H0+4)

// ---------------------------------------------------------------------------
__global__ void hist_kernel(const int* __restrict__ idx, int* __restrict__ cnt, int n)
{
    int i = blockIdx.x * blockDim.x + threadIdx.x;
    int stride = gridDim.x * blockDim.x;
    for (; i < n; i += stride) atomicAdd(&cnt[idx[i]], 1);
}

// batch is SORTED -> per-graph counts via two binary searches, no atomics.
__global__ void batch_count_kernel(const int* __restrict__ batch,
                                   int* __restrict__ cnt, int n)
{
    const int g = blockIdx.x * blockDim.x + threadIdx.x;
    if (g >= NG) return;
    int lo = 0, hi = n;
    while (lo < hi) { const int m = (lo + hi) >> 1; if (batch[m] < g) lo = m + 1; else hi = m; }
    const int start = lo;
    lo = 0; hi = n;
    while (lo < hi) { const int m = (lo + hi) >> 1; if (batch[m] < g + 1) lo = m + 1; else hi = m; }
    cnt[g] = lo - start;
}

__global__ void dinv_kernel(const int* __restrict__ deg, float* __restrict__ dinv, int n)
{
    int i = blockIdx.x * blockDim.x + threadIdx.x;
    if (i < n) dinv[i] = 1.0f / sqrtf((float)(deg[i] + 1));
}

// ---------------------------------------------------------------------------
// CSR build: exclusive scan of deg -> rowptr, then counting-sort src by dst.
__global__ __launch_bounds__(256) void scan1_kernel(
    const int* __restrict__ deg, int* __restrict__ rp, int* __restrict__ bsum, int n)
{
    __shared__ int tmp[256];
    const int t = threadIdx.x;
    const int i = blockIdx.x * 256 + t;
    int v = (i < n) ? deg[i] : 0;
    tmp[t] = v;
    __syncthreads();
    #pragma unroll
    for (int off = 1; off < 256; off <<= 1) {
        int a = (t >= off) ? tmp[t - off] : 0;
        __syncthreads();
        tmp[t] += a;
        __syncthreads();
    }
    if (i < n) rp[i] = tmp[t] - v;
    if (t == 255) bsum[blockIdx.x] = tmp[255];
}

__global__ __launch_bounds__(512) void scan2_kernel(
    const int* __restrict__ bsum, int* __restrict__ boff, int nb)
{
    __shared__ int tmp[512];
    const int t = threadIdx.x;
    int v = (t < nb) ? bsum[t] : 0;
    tmp[t] = v;
    __syncthreads();
    #pragma unroll
    for (int off = 1; off < 512; off <<= 1) {
        int a = (t >= off) ? tmp[t - off] : 0;
        __syncthreads();
        tmp[t] += a;
        __syncthreads();
    }
    if (t < nb) boff[t] = tmp[t] - v;
}

__global__ __launch_bounds__(256) void scan3_kernel(
    int* __restrict__ rp, int* __restrict__ wcur, const int* __restrict__ boff, int n)
{
    const int i = blockIdx.x * 256 + threadIdx.x;
    if (i < n) {
        const int v = rp[i] + boff[blockIdx.x];
        rp[i] = v;
        wcur[i] = v;
    }
}

__global__ void fill_kernel(const int* __restrict__ src, const int* __restrict__ dst,
                            int* __restrict__ wcur, int* __restrict__ csr, int ne)
{
    int i = blockIdx.x * blockDim.x + threadIdx.x;
    const int stride = gridDim.x * blockDim.x;
    for (; i < ne; i += stride) {
        const int d = dst[i];
        const int p = atomicAdd(&wcur[d], 1);
        csr[p] = src[i];
    }
}

// ---------------------------------------------------------------------------
// GEMM1: h0s[row] = (x[row] @ Wc0) * dinv[row]   [100k,128]@[128,64]
// Register-tiled 4x4. xs rows padded (+4 floats) so the 4 rsub broadcast
// groups land on distinct bank quads (4-way -> 2-way = free).
__global__ __launch_bounds__(256) void gemm1_kernel(
    const float* __restrict__ x, const float* __restrict__ W,
    const float* __restrict__ dinv, float* __restrict__ h0s, int n)
{
    __shared__ float Wl[FIN * H0];   // 32 KB [k][j]
    __shared__ float xs[BM * XP];    // 33 KB [r][k] padded
    const int t = threadIdx.x;
    for (int i = t; i < FIN * H0 / 4; i += 256)
        ((float4*)Wl)[i] = ((const float4*)W)[i];

    const int lane = t & 63;
    const int w    = t >> 6;              // 0..3
    const int rsub = lane >> 4;           // 0..3
    const int j0   = (lane & 15) * 4;     // col base (16 lanes -> 256B contig)
    const int wrow = w * 16 + rsub * 4;   // row base within tile
    const int ntiles = (n + BM - 1) / BM;

    for (int tile = blockIdx.x; tile < ntiles; tile += gridDim.x) {
        const int row0  = tile * BM;
        const int nrows = min(BM, n - row0);
        __syncthreads();                  // xs reuse fence
        {
            const float4* xg = (const float4*)(x + (size_t)row0 * FIN);
            const int nf4 = nrows * (FIN / 4);        // 2048 full tile
            for (int idx = t; idx < nf4; idx += 256) {
                const int r  = idx >> 5;              // FIN/4 = 32 f4/row
                const int c4 = idx & 31;
                *(float4*)&xs[r * XP + (c4 << 2)] = xg[idx];
            }
        }
        __syncthreads();

        float acc[4][4] = {};
        const float* xr = xs + wrow * XP;
        #pragma unroll 4
        for (int k = 0; k < FIN; k += 4) {
            const float4 w0 = *(const float4*)&Wl[(k + 0) * H0 + j0];
            const float4 w1 = *(const float4*)&Wl[(k + 1) * H0 + j0];
            const float4 w2 = *(const float4*)&Wl[(k + 2) * H0 + j0];
            const float4 w3 = *(const float4*)&Wl[(k + 3) * H0 + j0];
            #pragma unroll
            for (int r = 0; r < 4; ++r) {
                const float4 xv = *(const float4*)&xr[r * XP + k]; // 16-lane bcast
                acc[r][0] += xv.x * w0.x; acc[r][0] += xv.y * w1.x;
                acc[r][0] += xv.z * w2.x; acc[r][0] += xv.w * w3.x;
                acc[r][1] += xv.x * w0.y; acc[r][1] += xv.y * w1.y;
                acc[r][1] += xv.z * w2.y; acc[r][1] += xv.w * w3.y;
                acc[r][2] += xv.x * w0.z; acc[r][2] += xv.y * w1.z;
                acc[r][2] += xv.z * w2.z; acc[r][2] += xv.w * w3.z;
                acc[r][3] += xv.x * w0.w; acc[r][3] += xv.y * w1.w;
                acc[r][3] += xv.z * w2.w; acc[r][3] += xv.w * w3.w;
            }
        }
        #pragma unroll
        for (int r = 0; r < 4; ++r) {
            const int row = row0 + wrow + r;
            if (row < n) {
                const float dv = dinv[row];
                float4 o;
                o.x = acc[r][0] * dv; o.y = acc[r][1] * dv;
                o.z = acc[r][2] * dv; o.w = acc[r][3] * dv;
                *(float4*)&h0s[(size_t)row * H0 + j0] = o;
            }
        }
    }
}

// ---------------------------------------------------------------------------
// CSR gather (one wave per node, lane = feature). Rows pre-scaled by dinv[s]:
//   t = sum_{s in N(d)} hin[s] + hin[d]
// MODE 0: hout = relu(t*dinv[d] + bias) * dinv[d]   MODE 1: hout = t*dinv[d]
template <int MODE>
__global__ __launch_bounds__(256) void gather_kernel(
    const float* __restrict__ hin, const int* __restrict__ rowptr,
    const int* __restrict__ deg, const int* __restrict__ csr,
    const float* __restrict__ dinv, const float* __restrict__ bias,
    float* __restrict__ hout, int n)
{
    const int lane = threadIdx.x & 63;
    int wid = (blockIdx.x * blockDim.x + threadIdx.x) >> 6;
    const int nw = (gridDim.x * blockDim.x) >> 6;
    for (int d = wid; d < n; d += nw) {
        const int r0  = rowptr[d];
        const int cnt = deg[d];
        float acc = hin[(size_t)d * H0 + lane];
        int k = 0;
        for (; k + 1 < cnt; k += 2) {
            const int s0 = csr[r0 + k];
            const int s1 = csr[r0 + k + 1];
            acc += hin[(size_t)s0 * H0 + lane];
            acc += hin[(size_t)s1 * H0 + lane];
        }
        if (k < cnt) acc += hin[(size_t)csr[r0 + k] * H0 + lane];
        const float dv = dinv[d];
        if (MODE == 0)
            hout[(size_t)d * H0 + lane] = fmaxf(acc * dv + bias[lane], 0.f) * dv;
        else
            hout[(size_t)d * H0 + lane] = acc * dv;
    }
}

// ---------------------------------------------------------------------------
// GEMM2 [100k,64]@[64,128] + bias + relu + mean-pool. Register-tiled 4x8.
// Cols per thread: cA=(lane&15)*4 and cB=cA+64 -> W reads are 256B contiguous
// per 16 lanes (conflict-free); as rows padded +4 (4-way -> 2-way free).
__global__ __launch_bounds__(256) void gemm2_pool_kernel(
    const float* __restrict__ a /*agg1*/, const float* __restrict__ W /*64x128*/,
    const float* __restrict__ bc1, const int* __restrict__ batch,
    float* __restrict__ gsum, int n)
{
    __shared__ float Wl[H0 * H1];    // 32 KB [k][j]
    __shared__ float as[BM * AP];    // 17 KB [r][k] padded
    __shared__ float red[4][H1];     // 2 KB per-wave col partials
    __shared__ int   bs[BM];
    const int t = threadIdx.x;
    for (int i = t; i < H0 * H1 / 4; i += 256)
        ((float4*)Wl)[i] = ((const float4*)W)[i];

    const int lane = t & 63;
    const int w    = t >> 6;              // 0..3
    const int rsub = lane >> 4;           // 0..3
    const int cA   = (lane & 15) * 4;     // cols cA..cA+3
    const int cB   = cA + 64;             // cols cB..cB+3
    const int wrow = w * 16 + rsub * 4;   // row base within tile
    const float4 bA = *(const float4*)&bc1[cA];
    const float4 bB = *(const float4*)&bc1[cB];
    const int ntiles = (n + BM - 1) / BM;

    for (int tile = blockIdx.x; tile < ntiles; tile += gridDim.x) {
        const int row0  = tile * BM;
        const int nrows = min(BM, n - row0);
        __syncthreads();                  // as/red/bs reuse fence
        {
            const float4* ag = (const float4*)(a + (size_t)row0 * H0);
            const int nf4 = nrows * (H0 / 4);         // 1024 full tile
            for (int idx = t; idx < nf4; idx += 256) {
                const int r  = idx >> 4;              // H0/4 = 16 f4/row
                const int c4 = idx & 15;
                *(float4*)&as[r * AP + (c4 << 2)] = ag[idx];
            }
            if (t < nrows) bs[t] = batch[row0 + t];
        }
        __syncthreads();

        float acc[4][8] = {};
        const float* ar = as + wrow * AP;
        #pragma unroll 4
        for (int k = 0; k < H0; k += 4) {
            float4 wa[4], wb[4];
            #pragma unroll
            for (int kk = 0; kk < 4; ++kk) {
                wa[kk] = *(const float4*)&Wl[(k + kk) * H1 + cA];
                wb[kk] = *(const float4*)&Wl[(k + kk) * H1 + cB];
            }
            #pragma unroll
            for (int r = 0; r < 4; ++r) {
                const float4 xv = *(const float4*)&ar[r * AP + k]; // 16-lane bcast
                acc[r][0] += xv.x * wa[0].x; acc[r][0] += xv.y * wa[1].x;
                acc[r][0] += xv.z * wa[2].x; acc[r][0] += xv.w * wa[3].x;
                acc[r][1] += xv.x * wa[0].y; acc[r][1] += xv.y * wa[1].y;
                acc[r][1] += xv.z * wa[2].y; acc[r][1] += xv.w * wa[3].y;
                acc[r][2] += xv.x * wa[0].z; acc[r][2] += xv.y * wa[1].z;
                acc[r][2] += xv.z * wa[2].z; acc[r][2] += xv.w * wa[3].z;
                acc[r][3] += xv.x * wa[0].w; acc[r][3] += xv.y * wa[1].w;
                acc[r][3] += xv.z * wa[2].w; acc[r][3] += xv.w * wa[3].w;
                acc[r][4] += xv.x * wb[0].x; acc[r][4] += xv.y * wb[1].x;
                acc[r][4] += xv.z * wb[2].x; acc[r][4] += xv.w * wb[3].x;
                acc[r][5] += xv.x * wb[0].y; acc[r][5] += xv.y * wb[1].y;
                acc[r][5] += xv.z * wb[2].y; acc[r][5] += xv.w * wb[3].y;
                acc[r][6] += xv.x * wb[0].z; acc[r][6] += xv.y * wb[1].z;
                acc[r][6] += xv.z * wb[2].z; acc[r][6] += xv.w * wb[3].z;
                acc[r][7] += xv.x * wb[0].w; acc[r][7] += xv.y * wb[1].w;
                acc[r][7] += xv.z * wb[2].w; acc[r][7] += xv.w * wb[3].w;
            }
        }

        // bias+relu into per-row values, then pool (batch sorted).
        const float bv[8] = {bA.x, bA.y, bA.z, bA.w, bB.x, bB.y, bB.z, bB.w};
        const bool uni = (nrows == BM) && (bs[0] == bs[BM - 1]); // block-uniform
        if (uni) {
            float s[8];
            #pragma unroll
            for (int c = 0; c < 8; ++c) {
                s[c] = fmaxf(acc[0][c] + bv[c], 0.f) + fmaxf(acc[1][c] + bv[c], 0.f)
                     + fmaxf(acc[2][c] + bv[c], 0.f) + fmaxf(acc[3][c] + bv[c], 0.f);
                s[c] += __shfl_xor(s[c], 16);      // merge rsub pairs
                s[c] += __shfl_xor(s[c], 32);      // all 4 rsubs -> 16-row sum
            }
            if (rsub == 0) {
                #pragma unroll
                for (int c = 0; c < 4; ++c) red[w][cA + c] = s[c];
                #pragma unroll
                for (int c = 0; c < 4; ++c) red[w][cB + c] = s[c + 4];
            }
            __syncthreads();
            if (t < H1)
                atomicAdd(&gsum[(size_t)bs[0] * H1 + t],
                          red[0][t] + red[1][t] + red[2][t] + red[3][t]);
        } else {
            int gcur = -1; float run[8];
            #pragma unroll
            for (int r = 0; r < 4; ++r) {
                const int row = wrow + r;
                if (row < nrows) {
                    const int g = bs[row];
                    if (g != gcur) {
                        if (gcur >= 0) {
                            #pragma unroll
                            for (int c = 0; c < 4; ++c)
                                atomicAdd(&gsum[(size_t)gcur * H1 + cA + c], run[c]);
                            #pragma unroll
                            for (int c = 0; c < 4; ++c)
                                atomicAdd(&gsum[(size_t)gcur * H1 + cB + c], run[c + 4]);
                        }
                        gcur = g;
                        #pragma unroll
                        for (int c = 0; c < 8; ++c) run[c] = fmaxf(acc[r][c] + bv[c], 0.f);
                    } else {
                        #pragma unroll
                        for (int c = 0; c < 8; ++c) run[c] += fmaxf(acc[r][c] + bv[c], 0.f);
                    }
                }
            }
            if (gcur >= 0) {
                #pragma unroll
                for (int c = 0; c < 4; ++c)
                    atomicAdd(&gsum[(size_t)gcur * H1 + cA + c], run[c]);
                #pragma unroll
                for (int c = 0; c < 4; ++c)
                    atomicAdd(&gsum[(size_t)gcur * H1 + cB + c], run[c + 4]);
            }
        }
    }
}

// ---------------------------------------------------------------------------
// Per-graph MLP head: mean -> Linear(128,512) -> relu-Linear chain -> scalar
__global__ __launch_bounds__(256) void mlp_kernel(
    const float* __restrict__ gsum, const int* __restrict__ cnt,
    const float* __restrict__ Wf,  const float* __restrict__ bf,
    const float* __restrict__ Wh0, const float* __restrict__ bh0,
    const float* __restrict__ Wh1, const float* __restrict__ bh1,
    const float* __restrict__ Wh2, const float* __restrict__ bh2,
    const float* __restrict__ Wo,  const float* __restrict__ bo,
    float* __restrict__ out)
{
    __shared__ float gm[128];
    __shared__ float e0[512];
    __shared__ float e1[256];
    __shared__ float e2[128];
    __shared__ float e3[64];
    const int gi = blockIdx.x;
    const int t  = threadIdx.x;

    if (t < 128) {
        const int c = cnt[gi];
        gm[t] = gsum[gi * 128 + t] * (1.0f / (float)max(c, 1));
    }
    __syncthreads();

    for (int jj = t; jj < 512; jj += 256) {
        float acc = bf[jj];
        for (int k = 0; k < 128; ++k) acc += gm[k] * Wf[k * 512 + jj];
        e0[jj] = acc;
    }
    __syncthreads();

    {
        float acc = bh0[t];
        for (int k = 0; k < 512; ++k) acc += e0[k] * Wh0[k * 256 + t];
        if (t < 256) e1[t] = fmaxf(acc, 0.f);
    }
    __syncthreads();

    if (t < 128) {
        float acc = bh1[t];
        for (int k = 0; k < 256; ++k) acc += e1[k] * Wh1[k * 128 + t];
        e2[t] = fmaxf(acc, 0.f);
    }
    __syncthreads();

    if (t < 64) {
        float acc = bh2[t];
        for (int k = 0; k < 128; ++k) acc += e2[k] * Wh2[k * 64 + t];
        e3[t] = fmaxf(acc, 0.f);
    }
    __syncthreads();

    if (t < 64) {
        float p = e3[t] * Wo[t];
        #pragma unroll
        for (int off = 32; off > 0; off >>= 1) p += __shfl_down(p, off);
        if (t == 0) out[gi] = p + bo[0];
    }
}

// ---------------------------------------------------------------------------
extern "C" void kernel_launch(void* const* d_in, const int* in_sizes, int n_in,
                              void* d_out, int out_size, void* d_ws, size_t ws_size,
                              hipStream_t stream)
{
    const float* x    = (const float*)d_in[0];
    const int*   src  = (const int*)  d_in[1];
    const int*   dst  = (const int*)  d_in[2];
    const int*   batch= (const int*)  d_in[3];
    const float* Wc0  = (const float*)d_in[4];
    const float* bc0  = (const float*)d_in[5];
    const float* Wc1  = (const float*)d_in[6];
    const float* bc1  = (const float*)d_in[7];
    const float* Wf   = (const float*)d_in[8];
    const float* bf   = (const float*)d_in[9];
    const float* Wh0  = (const float*)d_in[10];
    const float* bh0  = (const float*)d_in[11];
    const float* Wh1  = (const float*)d_in[12];
    const float* bh1  = (const float*)d_in[13];
    const float* Wh2  = (const float*)d_in[14];
    const float* bh2  = (const float*)d_in[15];
    const float* Wo   = (const float*)d_in[16];
    const float* bo   = (const float*)d_in[17];
    float* out = (float*)d_out;

    const int n = NN, ne = NE;
    const int nblk = (n + 255) / 256;   // 391 scan blocks
    const int ntiles = (n + BM - 1) / BM;  // 1563

    char* ws = (char*)d_ws;
    size_t off = 0;
    auto alloc = [&](size_t bytes) {
        void* p = ws + off;
        off = (off + bytes + 255) & ~(size_t)255;
        return p;
    };
    int*   deg    = (int*)  alloc((size_t)n * 4);
    float* dinv   = (float*)alloc((size_t)n * 4);
    int*   rowptr = (int*)  alloc((size_t)n * 4);
    int*   wcur   = (int*)  alloc((size_t)n * 4);
    int*   bsum   = (int*)  alloc(512 * 4);
    int*   boff   = (int*)  alloc(512 * 4);
    int*   csr    = (int*)  alloc((size_t)ne * 4);
    float* h0s    = (float*)alloc((size_t)n * H0 * 4);
    float* h1s    = (float*)alloc((size_t)n * H0 * 4);
    float* agg1   = (float*)alloc((size_t)n * H0 * 4);
    float* gsum   = (float*)alloc((size_t)NG * H1 * 4);
    int*   cnt    = (int*)  alloc((size_t)NG * 4);

    hipMemsetAsync(deg,  0, (size_t)n * 4, stream);
    hipMemsetAsync(gsum, 0, (size_t)NG * H1 * 4, stream);

    // Degrees (random-address atomics) + batch counts (binary search).
    hist_kernel<<<1024, 256, 0, stream>>>(dst, deg, ne);
    batch_count_kernel<<<2, 256, 0, stream>>>(batch, cnt, n);
    dinv_kernel<<<nblk, 256, 0, stream>>>(deg, dinv, n);

    // CSR build (once, reused by both layers).
    scan1_kernel<<<nblk, 256, 0, stream>>>(deg, rowptr, bsum, n);
    scan2_kernel<<<1, 512, 0, stream>>>(bsum, boff, nblk);
    scan3_kernel<<<nblk, 256, 0, stream>>>(rowptr, wcur, boff, n);
    fill_kernel<<<1024, 256, 0, stream>>>(src, dst, wcur, csr, ne);

    // Layer 1: GEMM (128->64, pre-scaled by dinv), then CSR-gather aggregate.
    gemm1_kernel<<<ntiles, 256, 0, stream>>>(x, Wc0, dinv, h0s, n);
    gather_kernel<0><<<4096, 256, 0, stream>>>(h0s, rowptr, deg, csr, dinv, bc0, h1s, n);

    // Layer 2: aggregate FIRST (A'(hW) == (A'h)W at F=64), then GEMM 64->128
    // fused with bias+relu+mean-pool.
    gather_kernel<1><<<4096, 256, 0, stream>>>(h1s, rowptr, deg, csr, dinv, bc0, agg1, n);
    gemm2_pool_kernel<<<ntiles, 256, 0, stream>>>(agg1, Wc1, bc1, batch, gsum, n);

    // Per-graph MLP head.
    mlp_kernel<<<NG, 256, 0, stream>>>(gsum, cnt, Wf, bf, Wh0, bh0,
                                       Wh1, bh1, Wh2, bh2, Wo, bo, out);
}